// Round 15
// baseline (1813.233 us; speedup 1.0000x reference)
//
#include <hip/hip_runtime.h>
#include <hip/hip_bf16.h>
#include <cstddef>

// FAN_39273180955145 — round 25. r24 (739us k_fan, VGPR 124, zero spill):
// chain-pairing keeps landing ~1:1 (r21 -13, r23 -28, r24 -52). r25 pairs
// the remaining serial chains:
//  * qh producer et-PAIRING: qa0/qa1 chains share the bq load (2x ILP,
//    halves hL reads in that phase). 32 accum live.
//  * v producer 4-WIDE: va0..va3 share one avV load per kc (quarters vWT
//    reads). 64 accum live; oacc/sa not yet live -> peak unchanged.
//  * c_all dot split into 2 accumulators (64-deep serial FMA -> 2x32).
// Consumer stays 2-way (4-way = 128 accum = r14 spill shape); epilogue
// stays group-of-4 (r22: 32 live floats spill, 8 is safe). Everything else
// byte-identical to r24.

typedef unsigned short u16;
typedef unsigned int u32;
typedef short short8 __attribute__((ext_vector_type(8)));
typedef u32 u32x2 __attribute__((ext_vector_type(2)));
typedef float floatx16 __attribute__((ext_vector_type(16)));
typedef float f32x4 __attribute__((ext_vector_type(4)));

__device__ __forceinline__ float b2f(u16 u){ return __uint_as_float(((u32)u) << 16); }
__device__ __forceinline__ u16 f2b(float f){
  __hip_bfloat16 h = __float2bfloat16(f);          // RNE, = old manual round
  return *reinterpret_cast<u16*>(&h);
}
__device__ __forceinline__ u32 pk2(float a, float b){
  float2 t; t.x = a; t.y = b;
  __hip_bfloat162 h = __float22bfloat162_rn(t);    // v_cvt_pk_bf16_f32 (lo=a)
  return *reinterpret_cast<u32*>(&h);
}
// flagged input load: f32 ? fp32 : bf16; non-finite -> 0
__device__ __forceinline__ float ldf(const u16* p, size_t i, int f32){
  float v = f32 ? ((const float*)p)[i] : b2f(p[i]);
  return __builtin_isfinite(v) ? v : 0.f;
}
// [rows][128 bf16] region, 256B rows, 16B-chunk xor swizzle
__device__ __forceinline__ int swz(int row, int ch){ return (row << 8) | ((ch ^ (row & 15)) << 4); }
// [rows][256 bf16] region, 512B rows, 32 chunks; xor low4 only (bijective)
__device__ __forceinline__ int swz2(int row, int ch){ return (row << 9) | ((ch ^ (row & 15)) << 4); }
__device__ __forceinline__ floatx16 fz(){
  floatx16 z;
#pragma unroll
  for (int i = 0; i < 16; ++i) z[i] = 0.f;
  return z;
}
__device__ __forceinline__ floatx16 MF(short8 a, short8 b, floatx16 c){
  return __builtin_amdgcn_mfma_f32_32x32x16_bf16(a, b, c, 0, 0, 0);
}
// C-layout 32x32 tile (by value) -> k-chunk fragment via xor-32 exchange
// (r4-verified). cvt_pk packing + verified __shfl_xor lane exchange.
__device__ __forceinline__ short8 frag_from(floatx16 cv, int half, int q5){
  int r0 = half * 8;
  u32 e01 = pk2(cv[r0 + 0], cv[r0 + 1]);
  u32 e23 = pk2(cv[r0 + 2], cv[r0 + 3]);
  u32 o01 = pk2(cv[r0 + 4], cv[r0 + 5]);
  u32 o23 = pk2(cv[r0 + 6], cv[r0 + 7]);
  u32 s0 = q5 ? e01 : o01;
  u32 s1 = q5 ? e23 : o23;
  u32 r0v = __shfl_xor(s0, 32);
  u32 r1v = __shfl_xor(s1, 32);
  union { u32 u[4]; short8 v; } un;
  un.u[0] = q5 ? r0v : e01;
  un.u[1] = q5 ? r1v : e23;
  un.u[2] = q5 ? o01 : r0v;
  un.u[3] = q5 ? o23 : r1v;
  return un.v;
}

// ---------------- dtype detector (r4-verified) ----------------
__global__ __launch_bounds__(256) void k_detect(const u16* x, int* dflag){
  __shared__ int red[256];
  int t = threadIdx.x, cnt = 0;
  for (int i = t; i < 4096; i += 256){
    u16 v = x[2 * i];
    int e = (v >> 7) & 0xFF;
    if (e == 0xFF || e >= 0x90 || (e > 0 && e <= 0x20)) ++cnt;
  }
  red[t] = cnt;
  __syncthreads();
  for (int off = 128; off > 0; off >>= 1){
    if (t < off) red[t] += red[t + off];
    __syncthreads();
  }
  if (t == 0) dflag[0] = (red[0] > 1000) ? 1 : 0;
}

// ---------------- prep kernels ----------------

// MrowT[a][b] = M'[b,a]; vWT[d][e] = vW[e][d]; uv = u'.
__global__ __launch_bounds__(128) void k_prepw(const u16* qW, const u16* kW, const u16* vW,
                                               const u16* qb, u16* MrT, u16* vWT, float* uv,
                                               const int* dflag){
  int fl = dflag[0];
  int i = blockIdx.x >> 7, f = blockIdx.x & 127, e = threadIdx.x;
  size_t qo = (size_t)(i * 128 + e) * 128;   // qW row e
  size_t ko = (size_t)(i * 128 + f) * 128;   // kW row f
  float m = 0.f;
  for (int d = 0; d < 128; ++d) m += ldf(qW, qo + d, fl) * ldf(kW, ko + d, fl);
  const float RS = 0.08838834764831845f;  // 1/sqrt(128)
  MrT[(i * 128 + f) * 128 + e] = f2b(m * RS);                 // MrowT[f][e] = M'[e,f]
  vWT[(i * 128 + f) * 128 + e] = f2b(ldf(vW, qo + f, fl));    // vWT[d][e] = vW[e][d]
  __shared__ float red[128];
  red[e] = ldf(kW, ko + e, fl) * ldf(qb, (size_t)i * 128 + e, fl);
  __syncthreads();
  for (int off = 64; off > 0; off >>= 1){
    if (e < off) red[e] += red[e + off];
    __syncthreads();
  }
  if (e == 0) uv[i * 128 + f] = red[0] * RS;
}

__global__ __launch_bounds__(256) void k_h1t(const u16* h1W, u16* h1WT, const int* dflag){
  int fl = dflag[0];
  __shared__ u16 tile[64][130];
  int k0 = blockIdx.x * 64, tid = threadIdx.x;
#pragma unroll 4
  for (int it = 0; it < 32; ++it){
    int r = it * 2 + (tid >> 7), c = tid & 127;
    tile[r][c] = f2b(ldf(h1W, (size_t)(k0 + r) * 128 + c, fl));
  }
  __syncthreads();
#pragma unroll 4
  for (int it = 0; it < 32; ++it){
    int idx = it * 256 + tid, n = idx >> 6, kk = idx & 63;
    h1WT[(size_t)n * 32896 + k0 + kk] = tile[kk][n];
  }
}

// -------- fused embed + 2 attention layers; h in LDS; one block = one batch --------

__global__ __launch_bounds__(512, 2) void k_fan(
    const u16* x, const u16* sW, const u16* sb, const u16* hW, const u16* hbe,
    const u16* MrT, const float* uv, const u16* vWT, const u16* vb,
    const u16* lng, const u16* lnb,
    u16* hgq, u16* se, int qoff, const int* dflag){
  __shared__ alignas(16) u16 hL[32768];    // h   [256 s][128 f], swz,  64KB
  __shared__ alignas(16) u16 vt[32768];    // vT  [128 d][256 t], swz2, 64KB
  __shared__ alignas(16) float c_all[256]; // c_t + LKOFF - 8, whole layer
  __shared__ float u_lds[128];             // u' for current layer
  int fl = dflag[0];
  int bl = blockIdx.x;
  int b = qoff + bl;
  int tid = threadIdx.x, w = tid >> 6, lane = tid & 63, l31 = lane & 31, q5 = lane >> 5;
  size_t xo = (size_t)b * 272;
  const float LKOFF = -20.72326584f;       // ln(1e-9); off-diag log-kernel value

  // scalar embedding (lanes 0..127)
  if (tid < 128){
    float acc = ldf(sb, tid, fl);
#pragma unroll
    for (int j = 0; j < 16; ++j) acc += ldf(x, xo + j, fl) * ldf(sW, (size_t)j * 128 + tid, fl);
    se[(size_t)b * 128 + tid] = f2b(acc);
  }
  // history embedding -> hL (pair-packed cvt_pk)
#pragma unroll
  for (int it = 0; it < 8; ++it){
    int c = it * 512 + tid, s = c >> 4, ch = c & 15;
    float xv = ldf(x, xo + 16 + s, fl);
    float f[8];
#pragma unroll
    for (int j = 0; j < 8; ++j)
      f[j] = xv * ldf(hW, ch * 8 + j, fl) + ldf(hbe, ch * 8 + j, fl);
    union { u32 u[4]; short8 v; } rr_;
#pragma unroll
    for (int j2 = 0; j2 < 4; ++j2) rr_.u[j2] = pk2(f[2 * j2], f[2 * j2 + 1]);
    *(short8*)((char*)hL + swz(s, ch)) = rr_.v;
  }

  int mtv = w & 3;                         // d-chunk for v producer
  int scol = 32 * w + l31;

#pragma unroll 1
  for (int li = 0; li < 2; ++li){
    const u16* Ta   = MrT + li * 16384;
    const u16* vWTi = vWT + li * 16384;
    if (tid < 128) u_lds[tid] = uv[li * 128 + tid];
    float vbl = ldf(vb, (size_t)li * 128 + 32 * mtv + l31, fl);
    __syncthreads();                 // hL (embed/prev epilogue) + u_lds visible

    // ---- qh_s = h_s.M' into registers, et-PAIRED dual chains sharing bq.
    // D[e][s] tiles, lane = col = s = scol.
    short8 qhf[8];
#pragma unroll 1
    for (int ep = 0; ep < 2; ++ep){
      int et0 = 2 * ep, et1 = 2 * ep + 1;
      floatx16 qa0 = fz(), qa1 = fz();
#pragma unroll 2
      for (int kc = 0; kc < 8; ++kc){
        short8 av0 = *(const short8*)(Ta + (32 * et0 + l31) * 128 + kc * 16 + q5 * 8);
        short8 av1 = *(const short8*)(Ta + (32 * et1 + l31) * 128 + kc * 16 + q5 * 8);
        short8 bq  = *(const short8*)((char*)hL + swz(32 * w + l31, 2 * kc + q5));
        qa0 = MF(av0, bq, qa0);
        qa1 = MF(av1, bq, qa1);
      }
      qhf[2 * et0 + 0] = frag_from(qa0, 0, q5);   // e = 32et0 + 0..15
      qhf[2 * et0 + 1] = frag_from(qa0, 1, q5);   // e = 32et0 + 16..31
      qhf[2 * et1 + 0] = frag_from(qa1, 0, q5);
      qhf[2 * et1 + 1] = frag_from(qa1, 1, q5);
    }

    // ---- c_all[t] = u'.h_t + (LKOFF - 8)  [softmax baseline folded in]
    // dual FMA chains (dot0/dot1), reorder-only
    {
      int row = 32 * w + l31;
      float dot0 = 0.f, dot1 = 0.f;
#pragma unroll
      for (int kc = 0; kc < 4; ++kc){
        int chA = 2 * kc + q5, chB = 2 * (kc + 4) + q5;
        short8 hvA = *(const short8*)((char*)hL + swz(row, chA));
        short8 hvB = *(const short8*)((char*)hL + swz(row, chB));
#pragma unroll
        for (int j = 0; j < 8; ++j){
          dot0 += u_lds[chA * 8 + j] * b2f(hvA[j]);
          dot1 += u_lds[chB * 8 + j] * b2f(hvB[j]);
        }
      }
      float dot = dot0 + dot1;
      dot += __shfl_xor(dot, 32);
      if (q5 == 0) c_all[row] = dot + (LKOFF - 8.f);
    }

    // ---- v producer: whole layer, 4-WIDE chains sharing one avV load.
    // vt[d][t] = sum_e h[t,e] vW[e,d] + vb[d].
    {
      const u16* Va = vWTi + (32 * mtv + l31) * 128 + q5 * 8;
      int tcb = (w >> 2) * 4;
      floatx16 va0 = fz(), va1 = fz(), va2 = fz(), va3 = fz();
#pragma unroll 2
      for (int kc = 0; kc < 8; ++kc){
        short8 avV = *(const short8*)(Va + kc * 16);
        short8 bh0 = *(const short8*)((char*)hL + swz(32 * (tcb + 0) + l31, 2 * kc + q5));
        short8 bh1 = *(const short8*)((char*)hL + swz(32 * (tcb + 1) + l31, 2 * kc + q5));
        short8 bh2 = *(const short8*)((char*)hL + swz(32 * (tcb + 2) + l31, 2 * kc + q5));
        short8 bh3 = *(const short8*)((char*)hL + swz(32 * (tcb + 3) + l31, 2 * kc + q5));
        va0 = MF(bh0, avV, va0);
        va1 = MF(bh1, avV, va1);
        va2 = MF(bh2, avV, va2);
        va3 = MF(bh3, avV, va3);
      }
      // D[t][d]: lane = d-col, regs = t; 4 consecutive t -> one 8B chunk
#pragma unroll
      for (int u = 0; u < 4; ++u){
        floatx16 va = (u == 0) ? va0 : (u == 1) ? va1 : (u == 2) ? va2 : va3;
        int tc = tcb + u;
#pragma unroll
        for (int qd = 0; qd < 4; ++qd){
          u32x2 pv;
          pv.x = pk2(va[4 * qd + 0] + vbl, va[4 * qd + 1] + vbl);
          pv.y = pk2(va[4 * qd + 2] + vbl, va[4 * qd + 3] + vbl);
          *(u32x2*)((char*)vt + swz2(32 * mtv + l31, 4 * tc + qd) + 8 * q5) = pv;
        }
      }
    }
    __syncthreads();               // vt + c_all complete

    float ls00 = 0.f, ls01 = 0.f, ls10 = 0.f, ls11 = 0.f;
    floatx16 oacc[4];
#pragma unroll
    for (int nt = 0; nt < 4; ++nt) oacc[nt] = fz();

    // ---- consumer: mt-PAIRED scores + exp + P@V; NO internal barriers
#pragma unroll 1
    for (int mtp = 0; mtp < 4; ++mtp){
      int mt0 = 2 * mtp, mt1 = 2 * mtp + 1;
      floatx16 sa0 = fz(), sa1 = fz();
      __builtin_amdgcn_s_setprio(1);
#pragma unroll
      for (int kc = 0; kc < 8; ++kc){
        short8 ah0 = *(const short8*)((char*)hL + swz(32 * mt0 + l31, 2 * kc + q5));
        short8 ah1 = *(const short8*)((char*)hL + swz(32 * mt1 + l31, 2 * kc + q5));
        sa0 = MF(ah0, qhf[kc], sa0);
        sa1 = MF(ah1, qhf[kc], sa1);
      }
      __builtin_amdgcn_s_setprio(0);
      // softmax on sa0 (v = sa + c2[tg]; diag removes folded off-diag LKOFF)
#pragma unroll
      for (int g = 0; g < 4; ++g){
        f32x4 c4 = *(const f32x4*)&c_all[32 * mt0 + 8 * g + 4 * q5];
#pragma unroll
        for (int k = 0; k < 4; ++k){
          int reg = 4 * g + k;
          int tg = 32 * mt0 + 8 * g + 4 * q5 + k;
          float v = sa0[reg] + c4[k];
          if (tg == scol) v -= LKOFF;
          v = fminf(fmaxf(v, -58.f), 42.f);
          float p = __expf(v);
          sa0[reg] = p;
          if (reg & 1) ls01 += p; else ls00 += p;
        }
      }
      // softmax on sa1
#pragma unroll
      for (int g = 0; g < 4; ++g){
        f32x4 c4 = *(const f32x4*)&c_all[32 * mt1 + 8 * g + 4 * q5];
#pragma unroll
        for (int k = 0; k < 4; ++k){
          int reg = 4 * g + k;
          int tg = 32 * mt1 + 8 * g + 4 * q5 + k;
          float v = sa1[reg] + c4[k];
          if (tg == scol) v -= LKOFF;
          v = fminf(fmaxf(v, -58.f), 42.f);
          float p = __expf(v);
          sa1[reg] = p;
          if (reg & 1) ls11 += p; else ls10 += p;
        }
      }
      // pf frags BEFORE the bv loads so sa0/sa1 die here
      short8 pf00 = frag_from(sa0, 0, q5);
      short8 pf01 = frag_from(sa0, 1, q5);
      short8 pf10 = frag_from(sa1, 0, q5);
      short8 pf11 = frag_from(sa1, 1, q5);
      __builtin_amdgcn_s_setprio(1);
#pragma unroll
      for (int nt = 0; nt < 4; ++nt){
        short8 bv;
        bv = *(const short8*)((char*)vt + swz2(32 * nt + l31, 4 * mt0 + 0 + q5));
        oacc[nt] = MF(pf00, bv, oacc[nt]);
        bv = *(const short8*)((char*)vt + swz2(32 * nt + l31, 4 * mt0 + 2 + q5));
        oacc[nt] = MF(pf01, bv, oacc[nt]);
        bv = *(const short8*)((char*)vt + swz2(32 * nt + l31, 4 * mt1 + 0 + q5));
        oacc[nt] = MF(pf10, bv, oacc[nt]);
        bv = *(const short8*)((char*)vt + swz2(32 * nt + l31, 4 * mt1 + 2 + q5));
        oacc[nt] = MF(pf11, bv, oacc[nt]);
      }
      __builtin_amdgcn_s_setprio(0);
    }
    __syncthreads();                   // all hL reads done before epilogue writes

    // ---- epilogue: /l, +residual, LayerNorm, write back to hL (own rows only)
    // group-of-4 batched butterfly (r23): 8 independent shuffles per round.
    float ls_tot = (ls00 + ls01) + (ls10 + ls11);
    float l_run = ls_tot + __shfl_xor(ls_tot, 32);
    float linv = 1.f / l_run;
    float gv[4], bbv[4];
#pragma unroll
    for (int nt = 0; nt < 4; ++nt){
      gv[nt]  = ldf(lng, (size_t)li * 128 + 32 * nt + l31, fl);
      bbv[nt] = ldf(lnb, (size_t)li * 128 + 32 * nt + l31, fl);
    }
#pragma unroll 1
    for (int g4 = 0; g4 < 4; ++g4){
      float s1v[4], s2v[4];
      // pass 1: residual + scale, partials for the 4 regs of this group
#pragma unroll
      for (int j = 0; j < 4; ++j){
        int reg = 4 * g4 + j;
        int rr = (reg & 3) + 8 * (reg >> 2) + 4 * q5;
        int srow = 32 * w + rr;
        float lrv = __shfl(linv, rr);
        float s1 = 0.f, s2 = 0.f;
#pragma unroll
        for (int nt = 0; nt < 4; ++nt){
          int d = 32 * nt + l31;
          float res = b2f(*(const u16*)((char*)hL + swz(srow, d >> 3) + (d & 7) * 2));
          float v = oacc[nt][reg] * lrv + res;
          oacc[nt][reg] = v;
          s1 += v; s2 += v * v;
        }
        s1v[j] = s1; s2v[j] = s2;
      }
      // pass 2: batched butterfly, 8 independent shuffles per round
#pragma unroll
      for (int off = 1; off < 32; off <<= 1){
#pragma unroll
        for (int j = 0; j < 4; ++j){
          s1v[j] += __shfl_xor(s1v[j], off);
          s2v[j] += __shfl_xor(s2v[j], off);
        }
      }
      // pass 3: stats + normalize + write
#pragma unroll
      for (int j = 0; j < 4; ++j){
        int reg = 4 * g4 + j;
        int rr = (reg & 3) + 8 * (reg >> 2) + 4 * q5;
        int srow = 32 * w + rr;
        float mu = s1v[j] * 0.0078125f;
        float rs = rsqrtf(fmaxf(s2v[j] * 0.0078125f - mu * mu, 0.f) + 1e-5f);
#pragma unroll
        for (int nt = 0; nt < 4; ++nt){
          int d = 32 * nt + l31;
          float v = (oacc[nt][reg] - mu) * rs * gv[nt] + bbv[nt];
          *(u16*)((char*)hL + swz(srow, d >> 3) + (d & 7) * 2) = f2b(v);
        }
      }
    }
    __syncthreads();                   // hL update visible before next layer / store
  }

  // final h -> global, coalesced 16B chunks
#pragma unroll
  for (int it = 0; it < 8; ++it){
    int c = it * 512 + tid, row = c >> 4, ch = c & 15;
    *(short8*)(hgq + (size_t)bl * 32768 + row * 128 + ch * 8) =
        *(const short8*)((char*)hL + swz(row, ch));
  }
}

// ---------------- MLP head ----------------

__global__ __launch_bounds__(256) void k_mlp1(const u16* se, const u16* hgq, const u16* h1WT,
                                              float* part, int qoff, int nb){
  int mb = blockIdx.x, ks = blockIdx.y;
  int tid = threadIdx.x, w = tid >> 6, lane = tid & 63, l31 = lane & 31, q5 = lane >> 5;
  int b0 = mb * 32;
  floatx16 acc = fz();
  const u16* brow = h1WT + (size_t)(32 * w + l31) * 32896;
  int br = b0 + l31;
  const u16* seb = se + (size_t)(qoff + br) * 128;
  const u16* hb = hgq + (size_t)br * 32768;
  for (int kk = 0; kk < 257; ++kk){
    int kbase = ks * 4112 + kk * 16;
    const u16* ap = (kbase < 128) ? (seb + kbase + q5 * 8) : (hb + (kbase - 128) + q5 * 8);
    short8 a = *(const short8*)ap;
    short8 bf = *(const short8*)(brow + kbase + q5 * 8);
    acc = MF(a, bf, acc);
  }
#pragma unroll
  for (int reg = 0; reg < 16; ++reg){
    int rr = (reg & 3) + 8 * (reg >> 2) + 4 * q5;
    part[(size_t)ks * nb * 128 + (size_t)(b0 + rr) * 128 + 32 * w + l31] = acc[reg];
  }
}

__global__ __launch_bounds__(256) void k_mlp1red(const float* part, const u16* h1b, float* z1q,
                                                 const int* dflag, int nb){
  int fl = dflag[0];
  int idx = blockIdx.x * 256 + threadIdx.x;    // 0..nb*128-1
  float s = ldf(h1b, idx & 127, fl);
  size_t stride = (size_t)nb * 128;
#pragma unroll
  for (int ks = 0; ks < 8; ++ks) s += part[(size_t)ks * stride + idx];
  z1q[idx] = fmaxf(s, 0.f);
}

__global__ __launch_bounds__(256) void k_mlp2(const float* z1, const u16* h2W, const u16* h2b,
                                              float* z2, const int* dflag){
  int fl = dflag[0];
  int idx = blockIdx.x * 256 + threadIdx.x;    // 0..131071
  int b = idx >> 6, j = idx & 63;
  float s = ldf(h2b, j, fl);
  const float* zr = z1 + (size_t)b * 128;
  for (int k = 0; k < 128; ++k) s += zr[k] * ldf(h2W, (size_t)k * 64 + j, fl);
  z2[idx] = fmaxf(s, 0.f);
}

__global__ __launch_bounds__(256) void k_mlp3(const float* z2, const u16* h3W, const u16* h3b,
                                              void* out, const int* dflag){
  int fl = dflag[0];
  int b = blockIdx.x * 256 + threadIdx.x;      // 0..2047
  float s = ldf(h3b, 0, fl);
  const float* zr = z2 + (size_t)b * 64;
#pragma unroll
  for (int j = 0; j < 64; ++j) s += zr[j] * ldf(h3W, j, fl);
  if (!__builtin_isfinite(s)) s = 0.f;
  if (fl) ((float*)out)[b] = s;
  else    ((u16*)out)[b] = f2b(s);
}

// ---------------- launch ----------------

extern "C" void kernel_launch(void* const* d_in, const int* in_sizes, int n_in,
                              void* d_out, int out_size, void* d_ws, size_t ws_size,
                              hipStream_t stream) {
  const u16* x   = (const u16*)d_in[0];
  const u16* sW  = (const u16*)d_in[1];
  const u16* sb  = (const u16*)d_in[2];
  const u16* hW  = (const u16*)d_in[3];
  const u16* hb  = (const u16*)d_in[4];
  const u16* qW  = (const u16*)d_in[5];
  const u16* qb  = (const u16*)d_in[6];
  const u16* kW  = (const u16*)d_in[7];
  // d_in[8] = kb : cancels in softmax, unused
  const u16* vW  = (const u16*)d_in[9];
  const u16* vb  = (const u16*)d_in[10];
  const u16* lng = (const u16*)d_in[11];
  const u16* lnb = (const u16*)d_in[12];
  const u16* h1W = (const u16*)d_in[13];
  const u16* h1b = (const u16*)d_in[14];
  const u16* h2W = (const u16*)d_in[15];
  const u16* h2b = (const u16*)d_in[16];
  const u16* h3W = (const u16*)d_in[17];
  const u16* h3b = (const u16*)d_in[18];

  // full-pass mode (r5-r8 ran this branch); quarter mode fallback.
  const int nb = (ws_size >= 153600000ull) ? 2048 : 512;
  const int nq = 2048 / nb;

  char* W = (char*)d_ws;
  size_t o = 0;
  u16*   hg    = (u16*)(W + o); o += (size_t)nb * 65536;   // nb*32768*2
  u16*   h1WT  = (u16*)(W + o); o += 8421376;
  u16*   se    = (u16*)(W + o); o += 524288;               // always full 2048x128 bf16
  u16*   MrT   = (u16*)(W + o); o += 65536;
  u16*   vWT   = (u16*)(W + o); o += 65536;
  float* uv    = (float*)(W + o); o += 1024;
  float* part  = (float*)(W + o); o += (size_t)nb * 4096;  // 8 * nb*128 * 4B
  float* z1    = (float*)(W + o); o += 1048576;            // always full
  float* z2    = (float*)(W + o); o += 524288;
  int*   dflag = (int*)(W + o);

  k_detect<<<1, 256, 0, stream>>>(x, dflag);
  k_prepw<<<256, 128, 0, stream>>>(qW, kW, vW, qb, MrT, vWT, uv, dflag);
  k_h1t<<<514, 256, 0, stream>>>(h1W, h1WT, dflag);

  for (int q = 0; q < nq; ++q){
    int qoff = q * nb;
    k_fan<<<nb, 512, 0, stream>>>(x, sW, sb, hW, hb, MrT, uv, vWT, vb,
                                  lng, lnb, hg, se, qoff, dflag);
    k_mlp1<<<dim3(nb / 32, 8), 256, 0, stream>>>(se, hg, h1WT, part, qoff, nb);
    k_mlp1red<<<nb / 2, 256, 0, stream>>>(part, h1b, z1 + (size_t)qoff * 128, dflag, nb);
  }

  k_mlp2<<<512, 256, 0, stream>>>(z1, h2W, h2b, z2, dflag);
  k_mlp3<<<8, 256, 0, stream>>>(z2, h3W, h3b, d_out, dflag);
}

// Round 16
// 1790.418 us; speedup vs baseline: 1.0127x; 1.0127x over previous
//
#include <hip/hip_runtime.h>
#include <hip/hip_bf16.h>
#include <cstddef>

// FAN_39273180955145 — round 26. r25 catastrophically regressed (739->1687):
// the v-producer's whole-vector ternary select ((u==0)?va0:...) on a
// floatx16 likely materialized through scratch (rule-#20 shape: per-store
// ~900cyc round trips -> MfmaUtil 5%, 2.3x slowdown, small spill traffic).
// r26 = r24 exactly (739us proven), plus ONLY the two safe r25 pieces with
// fully static code:
//  * qh et-PAIRING: qa0/qa1 dual chains sharing bq; four explicitly named
//    frag_from stores (no vector selects). +32 accum in a low-pressure phase.
//  * c_all dual FMA chains (dot0/dot1, reorder-only).
//  * v producer: r24's 2-wide va0/va1 with explicit blocks (proven).
// Everything else byte-identical to r24 (mt-paired consumer, group-of-4 LN
// butterfly, cvt_pk packing, softmax folding, 3 barriers/layer, (512,2)).

typedef unsigned short u16;
typedef unsigned int u32;
typedef short short8 __attribute__((ext_vector_type(8)));
typedef u32 u32x2 __attribute__((ext_vector_type(2)));
typedef float floatx16 __attribute__((ext_vector_type(16)));
typedef float f32x4 __attribute__((ext_vector_type(4)));

__device__ __forceinline__ float b2f(u16 u){ return __uint_as_float(((u32)u) << 16); }
__device__ __forceinline__ u16 f2b(float f){
  __hip_bfloat16 h = __float2bfloat16(f);          // RNE, = old manual round
  return *reinterpret_cast<u16*>(&h);
}
__device__ __forceinline__ u32 pk2(float a, float b){
  float2 t; t.x = a; t.y = b;
  __hip_bfloat162 h = __float22bfloat162_rn(t);    // v_cvt_pk_bf16_f32 (lo=a)
  return *reinterpret_cast<u32*>(&h);
}
// flagged input load: f32 ? fp32 : bf16; non-finite -> 0
__device__ __forceinline__ float ldf(const u16* p, size_t i, int f32){
  float v = f32 ? ((const float*)p)[i] : b2f(p[i]);
  return __builtin_isfinite(v) ? v : 0.f;
}
// [rows][128 bf16] region, 256B rows, 16B-chunk xor swizzle
__device__ __forceinline__ int swz(int row, int ch){ return (row << 8) | ((ch ^ (row & 15)) << 4); }
// [rows][256 bf16] region, 512B rows, 32 chunks; xor low4 only (bijective)
__device__ __forceinline__ int swz2(int row, int ch){ return (row << 9) | ((ch ^ (row & 15)) << 4); }
__device__ __forceinline__ floatx16 fz(){
  floatx16 z;
#pragma unroll
  for (int i = 0; i < 16; ++i) z[i] = 0.f;
  return z;
}
__device__ __forceinline__ floatx16 MF(short8 a, short8 b, floatx16 c){
  return __builtin_amdgcn_mfma_f32_32x32x16_bf16(a, b, c, 0, 0, 0);
}
// C-layout 32x32 tile (by value) -> k-chunk fragment via xor-32 exchange
// (r4-verified). cvt_pk packing + verified __shfl_xor lane exchange.
__device__ __forceinline__ short8 frag_from(floatx16 cv, int half, int q5){
  int r0 = half * 8;
  u32 e01 = pk2(cv[r0 + 0], cv[r0 + 1]);
  u32 e23 = pk2(cv[r0 + 2], cv[r0 + 3]);
  u32 o01 = pk2(cv[r0 + 4], cv[r0 + 5]);
  u32 o23 = pk2(cv[r0 + 6], cv[r0 + 7]);
  u32 s0 = q5 ? e01 : o01;
  u32 s1 = q5 ? e23 : o23;
  u32 r0v = __shfl_xor(s0, 32);
  u32 r1v = __shfl_xor(s1, 32);
  union { u32 u[4]; short8 v; } un;
  un.u[0] = q5 ? r0v : e01;
  un.u[1] = q5 ? r1v : e23;
  un.u[2] = q5 ? o01 : r0v;
  un.u[3] = q5 ? o23 : r1v;
  return un.v;
}

// ---------------- dtype detector (r4-verified) ----------------
__global__ __launch_bounds__(256) void k_detect(const u16* x, int* dflag){
  __shared__ int red[256];
  int t = threadIdx.x, cnt = 0;
  for (int i = t; i < 4096; i += 256){
    u16 v = x[2 * i];
    int e = (v >> 7) & 0xFF;
    if (e == 0xFF || e >= 0x90 || (e > 0 && e <= 0x20)) ++cnt;
  }
  red[t] = cnt;
  __syncthreads();
  for (int off = 128; off > 0; off >>= 1){
    if (t < off) red[t] += red[t + off];
    __syncthreads();
  }
  if (t == 0) dflag[0] = (red[0] > 1000) ? 1 : 0;
}

// ---------------- prep kernels ----------------

// MrowT[a][b] = M'[b,a]; vWT[d][e] = vW[e][d]; uv = u'.
__global__ __launch_bounds__(128) void k_prepw(const u16* qW, const u16* kW, const u16* vW,
                                               const u16* qb, u16* MrT, u16* vWT, float* uv,
                                               const int* dflag){
  int fl = dflag[0];
  int i = blockIdx.x >> 7, f = blockIdx.x & 127, e = threadIdx.x;
  size_t qo = (size_t)(i * 128 + e) * 128;   // qW row e
  size_t ko = (size_t)(i * 128 + f) * 128;   // kW row f
  float m = 0.f;
  for (int d = 0; d < 128; ++d) m += ldf(qW, qo + d, fl) * ldf(kW, ko + d, fl);
  const float RS = 0.08838834764831845f;  // 1/sqrt(128)
  MrT[(i * 128 + f) * 128 + e] = f2b(m * RS);                 // MrowT[f][e] = M'[e,f]
  vWT[(i * 128 + f) * 128 + e] = f2b(ldf(vW, qo + f, fl));    // vWT[d][e] = vW[e][d]
  __shared__ float red[128];
  red[e] = ldf(kW, ko + e, fl) * ldf(qb, (size_t)i * 128 + e, fl);
  __syncthreads();
  for (int off = 64; off > 0; off >>= 1){
    if (e < off) red[e] += red[e + off];
    __syncthreads();
  }
  if (e == 0) uv[i * 128 + f] = red[0] * RS;
}

__global__ __launch_bounds__(256) void k_h1t(const u16* h1W, u16* h1WT, const int* dflag){
  int fl = dflag[0];
  __shared__ u16 tile[64][130];
  int k0 = blockIdx.x * 64, tid = threadIdx.x;
#pragma unroll 4
  for (int it = 0; it < 32; ++it){
    int r = it * 2 + (tid >> 7), c = tid & 127;
    tile[r][c] = f2b(ldf(h1W, (size_t)(k0 + r) * 128 + c, fl));
  }
  __syncthreads();
#pragma unroll 4
  for (int it = 0; it < 32; ++it){
    int idx = it * 256 + tid, n = idx >> 6, kk = idx & 63;
    h1WT[(size_t)n * 32896 + k0 + kk] = tile[kk][n];
  }
}

// -------- fused embed + 2 attention layers; h in LDS; one block = one batch --------

__global__ __launch_bounds__(512, 2) void k_fan(
    const u16* x, const u16* sW, const u16* sb, const u16* hW, const u16* hbe,
    const u16* MrT, const float* uv, const u16* vWT, const u16* vb,
    const u16* lng, const u16* lnb,
    u16* hgq, u16* se, int qoff, const int* dflag){
  __shared__ alignas(16) u16 hL[32768];    // h   [256 s][128 f], swz,  64KB
  __shared__ alignas(16) u16 vt[32768];    // vT  [128 d][256 t], swz2, 64KB
  __shared__ alignas(16) float c_all[256]; // c_t + LKOFF - 8, whole layer
  __shared__ float u_lds[128];             // u' for current layer
  int fl = dflag[0];
  int bl = blockIdx.x;
  int b = qoff + bl;
  int tid = threadIdx.x, w = tid >> 6, lane = tid & 63, l31 = lane & 31, q5 = lane >> 5;
  size_t xo = (size_t)b * 272;
  const float LKOFF = -20.72326584f;       // ln(1e-9); off-diag log-kernel value

  // scalar embedding (lanes 0..127)
  if (tid < 128){
    float acc = ldf(sb, tid, fl);
#pragma unroll
    for (int j = 0; j < 16; ++j) acc += ldf(x, xo + j, fl) * ldf(sW, (size_t)j * 128 + tid, fl);
    se[(size_t)b * 128 + tid] = f2b(acc);
  }
  // history embedding -> hL (pair-packed cvt_pk)
#pragma unroll
  for (int it = 0; it < 8; ++it){
    int c = it * 512 + tid, s = c >> 4, ch = c & 15;
    float xv = ldf(x, xo + 16 + s, fl);
    float f[8];
#pragma unroll
    for (int j = 0; j < 8; ++j)
      f[j] = xv * ldf(hW, ch * 8 + j, fl) + ldf(hbe, ch * 8 + j, fl);
    union { u32 u[4]; short8 v; } rr_;
#pragma unroll
    for (int j2 = 0; j2 < 4; ++j2) rr_.u[j2] = pk2(f[2 * j2], f[2 * j2 + 1]);
    *(short8*)((char*)hL + swz(s, ch)) = rr_.v;
  }

  int mtv = w & 3;                         // d-chunk for v producer
  int scol = 32 * w + l31;

#pragma unroll 1
  for (int li = 0; li < 2; ++li){
    const u16* Ta   = MrT + li * 16384;
    const u16* vWTi = vWT + li * 16384;
    if (tid < 128) u_lds[tid] = uv[li * 128 + tid];
    float vbl = ldf(vb, (size_t)li * 128 + 32 * mtv + l31, fl);
    __syncthreads();                 // hL (embed/prev epilogue) + u_lds visible

    // ---- qh_s = h_s.M' into registers, et-PAIRED dual chains sharing bq.
    // D[e][s] tiles, lane = col = s = scol. All frag stores explicit.
    short8 qhf[8];
#pragma unroll 1
    for (int ep = 0; ep < 2; ++ep){
      int et0 = 2 * ep, et1 = 2 * ep + 1;
      floatx16 qa0 = fz(), qa1 = fz();
#pragma unroll 2
      for (int kc = 0; kc < 8; ++kc){
        short8 av0 = *(const short8*)(Ta + (32 * et0 + l31) * 128 + kc * 16 + q5 * 8);
        short8 av1 = *(const short8*)(Ta + (32 * et1 + l31) * 128 + kc * 16 + q5 * 8);
        short8 bq  = *(const short8*)((char*)hL + swz(32 * w + l31, 2 * kc + q5));
        qa0 = MF(av0, bq, qa0);
        qa1 = MF(av1, bq, qa1);
      }
      qhf[4 * ep + 0] = frag_from(qa0, 0, q5);   // e = 32*et0 + 0..15
      qhf[4 * ep + 1] = frag_from(qa0, 1, q5);   // e = 32*et0 + 16..31
      qhf[4 * ep + 2] = frag_from(qa1, 0, q5);   // e = 32*et1 + 0..15
      qhf[4 * ep + 3] = frag_from(qa1, 1, q5);   // e = 32*et1 + 16..31
    }

    // ---- c_all[t] = u'.h_t + (LKOFF - 8); dual FMA chains (reorder-only)
    {
      int row = 32 * w + l31;
      float dot0 = 0.f, dot1 = 0.f;
#pragma unroll
      for (int kc = 0; kc < 4; ++kc){
        int chA = 2 * kc + q5, chB = 2 * (kc + 4) + q5;
        short8 hvA = *(const short8*)((char*)hL + swz(row, chA));
        short8 hvB = *(const short8*)((char*)hL + swz(row, chB));
#pragma unroll
        for (int j = 0; j < 8; ++j){
          dot0 += u_lds[chA * 8 + j] * b2f(hvA[j]);
          dot1 += u_lds[chB * 8 + j] * b2f(hvB[j]);
        }
      }
      float dot = dot0 + dot1;
      dot += __shfl_xor(dot, 32);
      if (q5 == 0) c_all[row] = dot + (LKOFF - 8.f);
    }

    // ---- v producer: whole layer, u-PAIRED dual chains sharing avV loads
    // (r24-proven shape, explicit va0/va1 blocks, NO vector selects).
    // vt[d][t] = sum_e h[t,e] vW[e,d] + vb[d].
    {
      const u16* Va = vWTi + (32 * mtv + l31) * 128 + q5 * 8;
#pragma unroll 1
      for (int up = 0; up < 2; ++up){
        int tc0 = (w >> 2) * 4 + 2 * up, tc1 = tc0 + 1;
        floatx16 va0 = fz(), va1 = fz();
#pragma unroll 2
        for (int kc = 0; kc < 8; ++kc){
          short8 avV = *(const short8*)(Va + kc * 16);
          short8 bh0 = *(const short8*)((char*)hL + swz(32 * tc0 + l31, 2 * kc + q5));
          short8 bh1 = *(const short8*)((char*)hL + swz(32 * tc1 + l31, 2 * kc + q5));
          va0 = MF(bh0, avV, va0);
          va1 = MF(bh1, avV, va1);
        }
        // D[t][d]: lane = d-col, regs = t; 4 consecutive t -> one 8B chunk
#pragma unroll
        for (int qd = 0; qd < 4; ++qd){
          u32x2 pv;
          pv.x = pk2(va0[4 * qd + 0] + vbl, va0[4 * qd + 1] + vbl);
          pv.y = pk2(va0[4 * qd + 2] + vbl, va0[4 * qd + 3] + vbl);
          *(u32x2*)((char*)vt + swz2(32 * mtv + l31, 4 * tc0 + qd) + 8 * q5) = pv;
        }
#pragma unroll
        for (int qd = 0; qd < 4; ++qd){
          u32x2 pv;
          pv.x = pk2(va1[4 * qd + 0] + vbl, va1[4 * qd + 1] + vbl);
          pv.y = pk2(va1[4 * qd + 2] + vbl, va1[4 * qd + 3] + vbl);
          *(u32x2*)((char*)vt + swz2(32 * mtv + l31, 4 * tc1 + qd) + 8 * q5) = pv;
        }
      }
    }
    __syncthreads();               // vt + c_all complete

    float ls00 = 0.f, ls01 = 0.f, ls10 = 0.f, ls11 = 0.f;
    floatx16 oacc[4];
#pragma unroll
    for (int nt = 0; nt < 4; ++nt) oacc[nt] = fz();

    // ---- consumer: mt-PAIRED scores + exp + P@V; NO internal barriers
#pragma unroll 1
    for (int mtp = 0; mtp < 4; ++mtp){
      int mt0 = 2 * mtp, mt1 = 2 * mtp + 1;
      floatx16 sa0 = fz(), sa1 = fz();
      __builtin_amdgcn_s_setprio(1);
#pragma unroll
      for (int kc = 0; kc < 8; ++kc){
        short8 ah0 = *(const short8*)((char*)hL + swz(32 * mt0 + l31, 2 * kc + q5));
        short8 ah1 = *(const short8*)((char*)hL + swz(32 * mt1 + l31, 2 * kc + q5));
        sa0 = MF(ah0, qhf[kc], sa0);
        sa1 = MF(ah1, qhf[kc], sa1);
      }
      __builtin_amdgcn_s_setprio(0);
      // softmax on sa0 (v = sa + c2[tg]; diag removes folded off-diag LKOFF)
#pragma unroll
      for (int g = 0; g < 4; ++g){
        f32x4 c4 = *(const f32x4*)&c_all[32 * mt0 + 8 * g + 4 * q5];
#pragma unroll
        for (int k = 0; k < 4; ++k){
          int reg = 4 * g + k;
          int tg = 32 * mt0 + 8 * g + 4 * q5 + k;
          float v = sa0[reg] + c4[k];
          if (tg == scol) v -= LKOFF;
          v = fminf(fmaxf(v, -58.f), 42.f);
          float p = __expf(v);
          sa0[reg] = p;
          if (reg & 1) ls01 += p; else ls00 += p;
        }
      }
      // softmax on sa1
#pragma unroll
      for (int g = 0; g < 4; ++g){
        f32x4 c4 = *(const f32x4*)&c_all[32 * mt1 + 8 * g + 4 * q5];
#pragma unroll
        for (int k = 0; k < 4; ++k){
          int reg = 4 * g + k;
          int tg = 32 * mt1 + 8 * g + 4 * q5 + k;
          float v = sa1[reg] + c4[k];
          if (tg == scol) v -= LKOFF;
          v = fminf(fmaxf(v, -58.f), 42.f);
          float p = __expf(v);
          sa1[reg] = p;
          if (reg & 1) ls11 += p; else ls10 += p;
        }
      }
      // pf frags BEFORE the bv loads so sa0/sa1 die here
      short8 pf00 = frag_from(sa0, 0, q5);
      short8 pf01 = frag_from(sa0, 1, q5);
      short8 pf10 = frag_from(sa1, 0, q5);
      short8 pf11 = frag_from(sa1, 1, q5);
      __builtin_amdgcn_s_setprio(1);
#pragma unroll
      for (int nt = 0; nt < 4; ++nt){
        short8 bv;
        bv = *(const short8*)((char*)vt + swz2(32 * nt + l31, 4 * mt0 + 0 + q5));
        oacc[nt] = MF(pf00, bv, oacc[nt]);
        bv = *(const short8*)((char*)vt + swz2(32 * nt + l31, 4 * mt0 + 2 + q5));
        oacc[nt] = MF(pf01, bv, oacc[nt]);
        bv = *(const short8*)((char*)vt + swz2(32 * nt + l31, 4 * mt1 + 0 + q5));
        oacc[nt] = MF(pf10, bv, oacc[nt]);
        bv = *(const short8*)((char*)vt + swz2(32 * nt + l31, 4 * mt1 + 2 + q5));
        oacc[nt] = MF(pf11, bv, oacc[nt]);
      }
      __builtin_amdgcn_s_setprio(0);
    }
    __syncthreads();                   // all hL reads done before epilogue writes

    // ---- epilogue: /l, +residual, LayerNorm, write back to hL (own rows only)
    // group-of-4 batched butterfly (r23): 8 independent shuffles per round.
    float ls_tot = (ls00 + ls01) + (ls10 + ls11);
    float l_run = ls_tot + __shfl_xor(ls_tot, 32);
    float linv = 1.f / l_run;
    float gv[4], bbv[4];
#pragma unroll
    for (int nt = 0; nt < 4; ++nt){
      gv[nt]  = ldf(lng, (size_t)li * 128 + 32 * nt + l31, fl);
      bbv[nt] = ldf(lnb, (size_t)li * 128 + 32 * nt + l31, fl);
    }
#pragma unroll 1
    for (int g4 = 0; g4 < 4; ++g4){
      float s1v[4], s2v[4];
      // pass 1: residual + scale, partials for the 4 regs of this group
#pragma unroll
      for (int j = 0; j < 4; ++j){
        int reg = 4 * g4 + j;
        int rr = (reg & 3) + 8 * (reg >> 2) + 4 * q5;
        int srow = 32 * w + rr;
        float lrv = __shfl(linv, rr);
        float s1 = 0.f, s2 = 0.f;
#pragma unroll
        for (int nt = 0; nt < 4; ++nt){
          int d = 32 * nt + l31;
          float res = b2f(*(const u16*)((char*)hL + swz(srow, d >> 3) + (d & 7) * 2));
          float v = oacc[nt][reg] * lrv + res;
          oacc[nt][reg] = v;
          s1 += v; s2 += v * v;
        }
        s1v[j] = s1; s2v[j] = s2;
      }
      // pass 2: batched butterfly, 8 independent shuffles per round
#pragma unroll
      for (int off = 1; off < 32; off <<= 1){
#pragma unroll
        for (int j = 0; j < 4; ++j){
          s1v[j] += __shfl_xor(s1v[j], off);
          s2v[j] += __shfl_xor(s2v[j], off);
        }
      }
      // pass 3: stats + normalize + write
#pragma unroll
      for (int j = 0; j < 4; ++j){
        int reg = 4 * g4 + j;
        int rr = (reg & 3) + 8 * (reg >> 2) + 4 * q5;
        int srow = 32 * w + rr;
        float mu = s1v[j] * 0.0078125f;
        float rs = rsqrtf(fmaxf(s2v[j] * 0.0078125f - mu * mu, 0.f) + 1e-5f);
#pragma unroll
        for (int nt = 0; nt < 4; ++nt){
          int d = 32 * nt + l31;
          float v = (oacc[nt][reg] - mu) * rs * gv[nt] + bbv[nt];
          *(u16*)((char*)hL + swz(srow, d >> 3) + (d & 7) * 2) = f2b(v);
        }
      }
    }
    __syncthreads();                   // hL update visible before next layer / store
  }

  // final h -> global, coalesced 16B chunks
#pragma unroll
  for (int it = 0; it < 8; ++it){
    int c = it * 512 + tid, row = c >> 4, ch = c & 15;
    *(short8*)(hgq + (size_t)bl * 32768 + row * 128 + ch * 8) =
        *(const short8*)((char*)hL + swz(row, ch));
  }
}

// ---------------- MLP head ----------------

__global__ __launch_bounds__(256) void k_mlp1(const u16* se, const u16* hgq, const u16* h1WT,
                                              float* part, int qoff, int nb){
  int mb = blockIdx.x, ks = blockIdx.y;
  int tid = threadIdx.x, w = tid >> 6, lane = tid & 63, l31 = lane & 31, q5 = lane >> 5;
  int b0 = mb * 32;
  floatx16 acc = fz();
  const u16* brow = h1WT + (size_t)(32 * w + l31) * 32896;
  int br = b0 + l31;
  const u16* seb = se + (size_t)(qoff + br) * 128;
  const u16* hb = hgq + (size_t)br * 32768;
  for (int kk = 0; kk < 257; ++kk){
    int kbase = ks * 4112 + kk * 16;
    const u16* ap = (kbase < 128) ? (seb + kbase + q5 * 8) : (hb + (kbase - 128) + q5 * 8);
    short8 a = *(const short8*)ap;
    short8 bf = *(const short8*)(brow + kbase + q5 * 8);
    acc = MF(a, bf, acc);
  }
#pragma unroll
  for (int reg = 0; reg < 16; ++reg){
    int rr = (reg & 3) + 8 * (reg >> 2) + 4 * q5;
    part[(size_t)ks * nb * 128 + (size_t)(b0 + rr) * 128 + 32 * w + l31] = acc[reg];
  }
}

__global__ __launch_bounds__(256) void k_mlp1red(const float* part, const u16* h1b, float* z1q,
                                                 const int* dflag, int nb){
  int fl = dflag[0];
  int idx = blockIdx.x * 256 + threadIdx.x;    // 0..nb*128-1
  float s = ldf(h1b, idx & 127, fl);
  size_t stride = (size_t)nb * 128;
#pragma unroll
  for (int ks = 0; ks < 8; ++ks) s += part[(size_t)ks * stride + idx];
  z1q[idx] = fmaxf(s, 0.f);
}

__global__ __launch_bounds__(256) void k_mlp2(const float* z1, const u16* h2W, const u16* h2b,
                                              float* z2, const int* dflag){
  int fl = dflag[0];
  int idx = blockIdx.x * 256 + threadIdx.x;    // 0..131071
  int b = idx >> 6, j = idx & 63;
  float s = ldf(h2b, j, fl);
  const float* zr = z1 + (size_t)b * 128;
  for (int k = 0; k < 128; ++k) s += zr[k] * ldf(h2W, (size_t)k * 64 + j, fl);
  z2[idx] = fmaxf(s, 0.f);
}

__global__ __launch_bounds__(256) void k_mlp3(const float* z2, const u16* h3W, const u16* h3b,
                                              void* out, const int* dflag){
  int fl = dflag[0];
  int b = blockIdx.x * 256 + threadIdx.x;      // 0..2047
  float s = ldf(h3b, 0, fl);
  const float* zr = z2 + (size_t)b * 64;
#pragma unroll
  for (int j = 0; j < 64; ++j) s += zr[j] * ldf(h3W, j, fl);
  if (!__builtin_isfinite(s)) s = 0.f;
  if (fl) ((float*)out)[b] = s;
  else    ((u16*)out)[b] = f2b(s);
}

// ---------------- launch ----------------

extern "C" void kernel_launch(void* const* d_in, const int* in_sizes, int n_in,
                              void* d_out, int out_size, void* d_ws, size_t ws_size,
                              hipStream_t stream) {
  const u16* x   = (const u16*)d_in[0];
  const u16* sW  = (const u16*)d_in[1];
  const u16* sb  = (const u16*)d_in[2];
  const u16* hW  = (const u16*)d_in[3];
  const u16* hb  = (const u16*)d_in[4];
  const u16* qW  = (const u16*)d_in[5];
  const u16* qb  = (const u16*)d_in[6];
  const u16* kW  = (const u16*)d_in[7];
  // d_in[8] = kb : cancels in softmax, unused
  const u16* vW  = (const u16*)d_in[9];
  const u16* vb  = (const u16*)d_in[10];
  const u16* lng = (const u16*)d_in[11];
  const u16* lnb = (const u16*)d_in[12];
  const u16* h1W = (const u16*)d_in[13];
  const u16* h1b = (const u16*)d_in[14];
  const u16* h2W = (const u16*)d_in[15];
  const u16* h2b = (const u16*)d_in[16];
  const u16* h3W = (const u16*)d_in[17];
  const u16* h3b = (const u16*)d_in[18];

  // full-pass mode (r5-r8 ran this branch); quarter mode fallback.
  const int nb = (ws_size >= 153600000ull) ? 2048 : 512;
  const int nq = 2048 / nb;

  char* W = (char*)d_ws;
  size_t o = 0;
  u16*   hg    = (u16*)(W + o); o += (size_t)nb * 65536;   // nb*32768*2
  u16*   h1WT  = (u16*)(W + o); o += 8421376;
  u16*   se    = (u16*)(W + o); o += 524288;               // always full 2048x128 bf16
  u16*   MrT   = (u16*)(W + o); o += 65536;
  u16*   vWT   = (u16*)(W + o); o += 65536;
  float* uv    = (float*)(W + o); o += 1024;
  float* part  = (float*)(W + o); o += (size_t)nb * 4096;  // 8 * nb*128 * 4B
  float* z1    = (float*)(W + o); o += 1048576;            // always full
  float* z2    = (float*)(W + o); o += 524288;
  int*   dflag = (int*)(W + o);

  k_detect<<<1, 256, 0, stream>>>(x, dflag);
  k_prepw<<<256, 128, 0, stream>>>(qW, kW, vW, qb, MrT, vWT, uv, dflag);
  k_h1t<<<514, 256, 0, stream>>>(h1W, h1WT, dflag);

  for (int q = 0; q < nq; ++q){
    int qoff = q * nb;
    k_fan<<<nb, 512, 0, stream>>>(x, sW, sb, hW, hb, MrT, uv, vWT, vb,
                                  lng, lnb, hg, se, qoff, dflag);
    k_mlp1<<<dim3(nb / 32, 8), 256, 0, stream>>>(se, hg, h1WT, part, qoff, nb);
    k_mlp1red<<<nb / 2, 256, 0, stream>>>(part, h1b, z1 + (size_t)qoff * 128, dflag, nb);
  }

  k_mlp2<<<512, 256, 0, stream>>>(z1, h2W, h2b, z2, dflag);
  k_mlp3<<<8, 256, 0, stream>>>(z2, h3W, h3b, d_out, dflag);
}

// Round 17
// 955.552 us; speedup vs baseline: 1.8976x; 1.8737x over previous
//
#include <hip/hip_runtime.h>
#include <hip/hip_bf16.h>
#include <cstddef>

// FAN_39273180955145 — round 27. r26 post-mortem: 1605us with ZERO HBM spill
// and MfmaUtil 5.3% -> rule-#20 violation, not register spill. r26's qh loop
// was "#pragma unroll 1 for(ep)" indexing qhf[4*ep+j] with RUNTIME ep ->
// qhf demoted to scratch/local (128B/thread, L2-resident = invisible in
// HBM-only FETCH/WRITE), and every consumer qhf[kc] read became a ~200cyc
// scratch load (64/layer/wave on the critical path). Same bug shape killed
// r25 (va ternary select). r24 was fast because its et loop was FULLY
// unrolled (static indices). r27 = r26 with the ep loop fully unrolled so
// qhf stays in registers. Everything else identical to r26/r24:
//  * qh et-PAIRED dual chains sharing bq (static frag stores).
//  * c_all dual FMA chains; v producer 2-wide va0/va1 (r24-proven).
//  * mt-paired consumer, group-of-4 LN butterfly, cvt_pk packing,
//    softmax folding, 3 barriers/layer, launch_bounds(512,2).

typedef unsigned short u16;
typedef unsigned int u32;
typedef short short8 __attribute__((ext_vector_type(8)));
typedef u32 u32x2 __attribute__((ext_vector_type(2)));
typedef float floatx16 __attribute__((ext_vector_type(16)));
typedef float f32x4 __attribute__((ext_vector_type(4)));

__device__ __forceinline__ float b2f(u16 u){ return __uint_as_float(((u32)u) << 16); }
__device__ __forceinline__ u16 f2b(float f){
  __hip_bfloat16 h = __float2bfloat16(f);          // RNE, = old manual round
  return *reinterpret_cast<u16*>(&h);
}
__device__ __forceinline__ u32 pk2(float a, float b){
  float2 t; t.x = a; t.y = b;
  __hip_bfloat162 h = __float22bfloat162_rn(t);    // v_cvt_pk_bf16_f32 (lo=a)
  return *reinterpret_cast<u32*>(&h);
}
// flagged input load: f32 ? fp32 : bf16; non-finite -> 0
__device__ __forceinline__ float ldf(const u16* p, size_t i, int f32){
  float v = f32 ? ((const float*)p)[i] : b2f(p[i]);
  return __builtin_isfinite(v) ? v : 0.f;
}
// [rows][128 bf16] region, 256B rows, 16B-chunk xor swizzle
__device__ __forceinline__ int swz(int row, int ch){ return (row << 8) | ((ch ^ (row & 15)) << 4); }
// [rows][256 bf16] region, 512B rows, 32 chunks; xor low4 only (bijective)
__device__ __forceinline__ int swz2(int row, int ch){ return (row << 9) | ((ch ^ (row & 15)) << 4); }
__device__ __forceinline__ floatx16 fz(){
  floatx16 z;
#pragma unroll
  for (int i = 0; i < 16; ++i) z[i] = 0.f;
  return z;
}
__device__ __forceinline__ floatx16 MF(short8 a, short8 b, floatx16 c){
  return __builtin_amdgcn_mfma_f32_32x32x16_bf16(a, b, c, 0, 0, 0);
}
// C-layout 32x32 tile (by value) -> k-chunk fragment via xor-32 exchange
// (r4-verified). cvt_pk packing + verified __shfl_xor lane exchange.
__device__ __forceinline__ short8 frag_from(floatx16 cv, int half, int q5){
  int r0 = half * 8;
  u32 e01 = pk2(cv[r0 + 0], cv[r0 + 1]);
  u32 e23 = pk2(cv[r0 + 2], cv[r0 + 3]);
  u32 o01 = pk2(cv[r0 + 4], cv[r0 + 5]);
  u32 o23 = pk2(cv[r0 + 6], cv[r0 + 7]);
  u32 s0 = q5 ? e01 : o01;
  u32 s1 = q5 ? e23 : o23;
  u32 r0v = __shfl_xor(s0, 32);
  u32 r1v = __shfl_xor(s1, 32);
  union { u32 u[4]; short8 v; } un;
  un.u[0] = q5 ? r0v : e01;
  un.u[1] = q5 ? r1v : e23;
  un.u[2] = q5 ? o01 : r0v;
  un.u[3] = q5 ? o23 : r1v;
  return un.v;
}

// ---------------- dtype detector (r4-verified) ----------------
__global__ __launch_bounds__(256) void k_detect(const u16* x, int* dflag){
  __shared__ int red[256];
  int t = threadIdx.x, cnt = 0;
  for (int i = t; i < 4096; i += 256){
    u16 v = x[2 * i];
    int e = (v >> 7) & 0xFF;
    if (e == 0xFF || e >= 0x90 || (e > 0 && e <= 0x20)) ++cnt;
  }
  red[t] = cnt;
  __syncthreads();
  for (int off = 128; off > 0; off >>= 1){
    if (t < off) red[t] += red[t + off];
    __syncthreads();
  }
  if (t == 0) dflag[0] = (red[0] > 1000) ? 1 : 0;
}

// ---------------- prep kernels ----------------

// MrowT[a][b] = M'[b,a]; vWT[d][e] = vW[e][d]; uv = u'.
__global__ __launch_bounds__(128) void k_prepw(const u16* qW, const u16* kW, const u16* vW,
                                               const u16* qb, u16* MrT, u16* vWT, float* uv,
                                               const int* dflag){
  int fl = dflag[0];
  int i = blockIdx.x >> 7, f = blockIdx.x & 127, e = threadIdx.x;
  size_t qo = (size_t)(i * 128 + e) * 128;   // qW row e
  size_t ko = (size_t)(i * 128 + f) * 128;   // kW row f
  float m = 0.f;
  for (int d = 0; d < 128; ++d) m += ldf(qW, qo + d, fl) * ldf(kW, ko + d, fl);
  const float RS = 0.08838834764831845f;  // 1/sqrt(128)
  MrT[(i * 128 + f) * 128 + e] = f2b(m * RS);                 // MrowT[f][e] = M'[e,f]
  vWT[(i * 128 + f) * 128 + e] = f2b(ldf(vW, qo + f, fl));    // vWT[d][e] = vW[e][d]
  __shared__ float red[128];
  red[e] = ldf(kW, ko + e, fl) * ldf(qb, (size_t)i * 128 + e, fl);
  __syncthreads();
  for (int off = 64; off > 0; off >>= 1){
    if (e < off) red[e] += red[e + off];
    __syncthreads();
  }
  if (e == 0) uv[i * 128 + f] = red[0] * RS;
}

__global__ __launch_bounds__(256) void k_h1t(const u16* h1W, u16* h1WT, const int* dflag){
  int fl = dflag[0];
  __shared__ u16 tile[64][130];
  int k0 = blockIdx.x * 64, tid = threadIdx.x;
#pragma unroll 4
  for (int it = 0; it < 32; ++it){
    int r = it * 2 + (tid >> 7), c = tid & 127;
    tile[r][c] = f2b(ldf(h1W, (size_t)(k0 + r) * 128 + c, fl));
  }
  __syncthreads();
#pragma unroll 4
  for (int it = 0; it < 32; ++it){
    int idx = it * 256 + tid, n = idx >> 6, kk = idx & 63;
    h1WT[(size_t)n * 32896 + k0 + kk] = tile[kk][n];
  }
}

// -------- fused embed + 2 attention layers; h in LDS; one block = one batch --------

__global__ __launch_bounds__(512, 2) void k_fan(
    const u16* x, const u16* sW, const u16* sb, const u16* hW, const u16* hbe,
    const u16* MrT, const float* uv, const u16* vWT, const u16* vb,
    const u16* lng, const u16* lnb,
    u16* hgq, u16* se, int qoff, const int* dflag){
  __shared__ alignas(16) u16 hL[32768];    // h   [256 s][128 f], swz,  64KB
  __shared__ alignas(16) u16 vt[32768];    // vT  [128 d][256 t], swz2, 64KB
  __shared__ alignas(16) float c_all[256]; // c_t + LKOFF - 8, whole layer
  __shared__ float u_lds[128];             // u' for current layer
  int fl = dflag[0];
  int bl = blockIdx.x;
  int b = qoff + bl;
  int tid = threadIdx.x, w = tid >> 6, lane = tid & 63, l31 = lane & 31, q5 = lane >> 5;
  size_t xo = (size_t)b * 272;
  const float LKOFF = -20.72326584f;       // ln(1e-9); off-diag log-kernel value

  // scalar embedding (lanes 0..127)
  if (tid < 128){
    float acc = ldf(sb, tid, fl);
#pragma unroll
    for (int j = 0; j < 16; ++j) acc += ldf(x, xo + j, fl) * ldf(sW, (size_t)j * 128 + tid, fl);
    se[(size_t)b * 128 + tid] = f2b(acc);
  }
  // history embedding -> hL (pair-packed cvt_pk)
#pragma unroll
  for (int it = 0; it < 8; ++it){
    int c = it * 512 + tid, s = c >> 4, ch = c & 15;
    float xv = ldf(x, xo + 16 + s, fl);
    float f[8];
#pragma unroll
    for (int j = 0; j < 8; ++j)
      f[j] = xv * ldf(hW, ch * 8 + j, fl) + ldf(hbe, ch * 8 + j, fl);
    union { u32 u[4]; short8 v; } rr_;
#pragma unroll
    for (int j2 = 0; j2 < 4; ++j2) rr_.u[j2] = pk2(f[2 * j2], f[2 * j2 + 1]);
    *(short8*)((char*)hL + swz(s, ch)) = rr_.v;
  }

  int mtv = w & 3;                         // d-chunk for v producer
  int scol = 32 * w + l31;

#pragma unroll 1
  for (int li = 0; li < 2; ++li){
    const u16* Ta   = MrT + li * 16384;
    const u16* vWTi = vWT + li * 16384;
    if (tid < 128) u_lds[tid] = uv[li * 128 + tid];
    float vbl = ldf(vb, (size_t)li * 128 + 32 * mtv + l31, fl);
    __syncthreads();                 // hL (embed/prev epilogue) + u_lds visible

    // ---- qh_s = h_s.M' into registers, et-PAIRED dual chains sharing bq.
    // D[e][s] tiles, lane = col = s = scol. FULLY UNROLLED (static qhf idx —
    // r26's "#pragma unroll 1" demoted qhf to scratch, rule #20).
    short8 qhf[8];
#pragma unroll
    for (int ep = 0; ep < 2; ++ep){
      int et0 = 2 * ep, et1 = 2 * ep + 1;
      floatx16 qa0 = fz(), qa1 = fz();
#pragma unroll 2
      for (int kc = 0; kc < 8; ++kc){
        short8 av0 = *(const short8*)(Ta + (32 * et0 + l31) * 128 + kc * 16 + q5 * 8);
        short8 av1 = *(const short8*)(Ta + (32 * et1 + l31) * 128 + kc * 16 + q5 * 8);
        short8 bq  = *(const short8*)((char*)hL + swz(32 * w + l31, 2 * kc + q5));
        qa0 = MF(av0, bq, qa0);
        qa1 = MF(av1, bq, qa1);
      }
      qhf[4 * ep + 0] = frag_from(qa0, 0, q5);   // e = 32*et0 + 0..15
      qhf[4 * ep + 1] = frag_from(qa0, 1, q5);   // e = 32*et0 + 16..31
      qhf[4 * ep + 2] = frag_from(qa1, 0, q5);   // e = 32*et1 + 0..15
      qhf[4 * ep + 3] = frag_from(qa1, 1, q5);   // e = 32*et1 + 16..31
    }

    // ---- c_all[t] = u'.h_t + (LKOFF - 8); dual FMA chains (reorder-only)
    {
      int row = 32 * w + l31;
      float dot0 = 0.f, dot1 = 0.f;
#pragma unroll
      for (int kc = 0; kc < 4; ++kc){
        int chA = 2 * kc + q5, chB = 2 * (kc + 4) + q5;
        short8 hvA = *(const short8*)((char*)hL + swz(row, chA));
        short8 hvB = *(const short8*)((char*)hL + swz(row, chB));
#pragma unroll
        for (int j = 0; j < 8; ++j){
          dot0 += u_lds[chA * 8 + j] * b2f(hvA[j]);
          dot1 += u_lds[chB * 8 + j] * b2f(hvB[j]);
        }
      }
      float dot = dot0 + dot1;
      dot += __shfl_xor(dot, 32);
      if (q5 == 0) c_all[row] = dot + (LKOFF - 8.f);
    }

    // ---- v producer: whole layer, u-PAIRED dual chains sharing avV loads
    // (r24-proven shape, explicit va0/va1 blocks, NO vector selects).
    // vt[d][t] = sum_e h[t,e] vW[e,d] + vb[d].
    {
      const u16* Va = vWTi + (32 * mtv + l31) * 128 + q5 * 8;
#pragma unroll 1
      for (int up = 0; up < 2; ++up){
        int tc0 = (w >> 2) * 4 + 2 * up, tc1 = tc0 + 1;
        floatx16 va0 = fz(), va1 = fz();
#pragma unroll 2
        for (int kc = 0; kc < 8; ++kc){
          short8 avV = *(const short8*)(Va + kc * 16);
          short8 bh0 = *(const short8*)((char*)hL + swz(32 * tc0 + l31, 2 * kc + q5));
          short8 bh1 = *(const short8*)((char*)hL + swz(32 * tc1 + l31, 2 * kc + q5));
          va0 = MF(bh0, avV, va0);
          va1 = MF(bh1, avV, va1);
        }
        // D[t][d]: lane = d-col, regs = t; 4 consecutive t -> one 8B chunk
#pragma unroll
        for (int qd = 0; qd < 4; ++qd){
          u32x2 pv;
          pv.x = pk2(va0[4 * qd + 0] + vbl, va0[4 * qd + 1] + vbl);
          pv.y = pk2(va0[4 * qd + 2] + vbl, va0[4 * qd + 3] + vbl);
          *(u32x2*)((char*)vt + swz2(32 * mtv + l31, 4 * tc0 + qd) + 8 * q5) = pv;
        }
#pragma unroll
        for (int qd = 0; qd < 4; ++qd){
          u32x2 pv;
          pv.x = pk2(va1[4 * qd + 0] + vbl, va1[4 * qd + 1] + vbl);
          pv.y = pk2(va1[4 * qd + 2] + vbl, va1[4 * qd + 3] + vbl);
          *(u32x2*)((char*)vt + swz2(32 * mtv + l31, 4 * tc1 + qd) + 8 * q5) = pv;
        }
      }
    }
    __syncthreads();               // vt + c_all complete

    float ls00 = 0.f, ls01 = 0.f, ls10 = 0.f, ls11 = 0.f;
    floatx16 oacc[4];
#pragma unroll
    for (int nt = 0; nt < 4; ++nt) oacc[nt] = fz();

    // ---- consumer: mt-PAIRED scores + exp + P@V; NO internal barriers
#pragma unroll 1
    for (int mtp = 0; mtp < 4; ++mtp){
      int mt0 = 2 * mtp, mt1 = 2 * mtp + 1;
      floatx16 sa0 = fz(), sa1 = fz();
      __builtin_amdgcn_s_setprio(1);
#pragma unroll
      for (int kc = 0; kc < 8; ++kc){
        short8 ah0 = *(const short8*)((char*)hL + swz(32 * mt0 + l31, 2 * kc + q5));
        short8 ah1 = *(const short8*)((char*)hL + swz(32 * mt1 + l31, 2 * kc + q5));
        sa0 = MF(ah0, qhf[kc], sa0);
        sa1 = MF(ah1, qhf[kc], sa1);
      }
      __builtin_amdgcn_s_setprio(0);
      // softmax on sa0 (v = sa + c2[tg]; diag removes folded off-diag LKOFF)
#pragma unroll
      for (int g = 0; g < 4; ++g){
        f32x4 c4 = *(const f32x4*)&c_all[32 * mt0 + 8 * g + 4 * q5];
#pragma unroll
        for (int k = 0; k < 4; ++k){
          int reg = 4 * g + k;
          int tg = 32 * mt0 + 8 * g + 4 * q5 + k;
          float v = sa0[reg] + c4[k];
          if (tg == scol) v -= LKOFF;
          v = fminf(fmaxf(v, -58.f), 42.f);
          float p = __expf(v);
          sa0[reg] = p;
          if (reg & 1) ls01 += p; else ls00 += p;
        }
      }
      // softmax on sa1
#pragma unroll
      for (int g = 0; g < 4; ++g){
        f32x4 c4 = *(const f32x4*)&c_all[32 * mt1 + 8 * g + 4 * q5];
#pragma unroll
        for (int k = 0; k < 4; ++k){
          int reg = 4 * g + k;
          int tg = 32 * mt1 + 8 * g + 4 * q5 + k;
          float v = sa1[reg] + c4[k];
          if (tg == scol) v -= LKOFF;
          v = fminf(fmaxf(v, -58.f), 42.f);
          float p = __expf(v);
          sa1[reg] = p;
          if (reg & 1) ls11 += p; else ls10 += p;
        }
      }
      // pf frags BEFORE the bv loads so sa0/sa1 die here
      short8 pf00 = frag_from(sa0, 0, q5);
      short8 pf01 = frag_from(sa0, 1, q5);
      short8 pf10 = frag_from(sa1, 0, q5);
      short8 pf11 = frag_from(sa1, 1, q5);
      __builtin_amdgcn_s_setprio(1);
#pragma unroll
      for (int nt = 0; nt < 4; ++nt){
        short8 bv;
        bv = *(const short8*)((char*)vt + swz2(32 * nt + l31, 4 * mt0 + 0 + q5));
        oacc[nt] = MF(pf00, bv, oacc[nt]);
        bv = *(const short8*)((char*)vt + swz2(32 * nt + l31, 4 * mt0 + 2 + q5));
        oacc[nt] = MF(pf01, bv, oacc[nt]);
        bv = *(const short8*)((char*)vt + swz2(32 * nt + l31, 4 * mt1 + 0 + q5));
        oacc[nt] = MF(pf10, bv, oacc[nt]);
        bv = *(const short8*)((char*)vt + swz2(32 * nt + l31, 4 * mt1 + 2 + q5));
        oacc[nt] = MF(pf11, bv, oacc[nt]);
      }
      __builtin_amdgcn_s_setprio(0);
    }
    __syncthreads();                   // all hL reads done before epilogue writes

    // ---- epilogue: /l, +residual, LayerNorm, write back to hL (own rows only)
    // group-of-4 batched butterfly (r23): 8 independent shuffles per round.
    float ls_tot = (ls00 + ls01) + (ls10 + ls11);
    float l_run = ls_tot + __shfl_xor(ls_tot, 32);
    float linv = 1.f / l_run;
    float gv[4], bbv[4];
#pragma unroll
    for (int nt = 0; nt < 4; ++nt){
      gv[nt]  = ldf(lng, (size_t)li * 128 + 32 * nt + l31, fl);
      bbv[nt] = ldf(lnb, (size_t)li * 128 + 32 * nt + l31, fl);
    }
#pragma unroll 1
    for (int g4 = 0; g4 < 4; ++g4){
      float s1v[4], s2v[4];
      // pass 1: residual + scale, partials for the 4 regs of this group
#pragma unroll
      for (int j = 0; j < 4; ++j){
        int reg = 4 * g4 + j;
        int rr = (reg & 3) + 8 * (reg >> 2) + 4 * q5;
        int srow = 32 * w + rr;
        float lrv = __shfl(linv, rr);
        float s1 = 0.f, s2 = 0.f;
#pragma unroll
        for (int nt = 0; nt < 4; ++nt){
          int d = 32 * nt + l31;
          float res = b2f(*(const u16*)((char*)hL + swz(srow, d >> 3) + (d & 7) * 2));
          float v = oacc[nt][reg] * lrv + res;
          oacc[nt][reg] = v;
          s1 += v; s2 += v * v;
        }
        s1v[j] = s1; s2v[j] = s2;
      }
      // pass 2: batched butterfly, 8 independent shuffles per round
#pragma unroll
      for (int off = 1; off < 32; off <<= 1){
#pragma unroll
        for (int j = 0; j < 4; ++j){
          s1v[j] += __shfl_xor(s1v[j], off);
          s2v[j] += __shfl_xor(s2v[j], off);
        }
      }
      // pass 3: stats + normalize + write
#pragma unroll
      for (int j = 0; j < 4; ++j){
        int reg = 4 * g4 + j;
        int rr = (reg & 3) + 8 * (reg >> 2) + 4 * q5;
        int srow = 32 * w + rr;
        float mu = s1v[j] * 0.0078125f;
        float rs = rsqrtf(fmaxf(s2v[j] * 0.0078125f - mu * mu, 0.f) + 1e-5f);
#pragma unroll
        for (int nt = 0; nt < 4; ++nt){
          int d = 32 * nt + l31;
          float v = (oacc[nt][reg] - mu) * rs * gv[nt] + bbv[nt];
          *(u16*)((char*)hL + swz(srow, d >> 3) + (d & 7) * 2) = f2b(v);
        }
      }
    }
    __syncthreads();                   // hL update visible before next layer / store
  }

  // final h -> global, coalesced 16B chunks
#pragma unroll
  for (int it = 0; it < 8; ++it){
    int c = it * 512 + tid, row = c >> 4, ch = c & 15;
    *(short8*)(hgq + (size_t)bl * 32768 + row * 128 + ch * 8) =
        *(const short8*)((char*)hL + swz(row, ch));
  }
}

// ---------------- MLP head ----------------

__global__ __launch_bounds__(256) void k_mlp1(const u16* se, const u16* hgq, const u16* h1WT,
                                              float* part, int qoff, int nb){
  int mb = blockIdx.x, ks = blockIdx.y;
  int tid = threadIdx.x, w = tid >> 6, lane = tid & 63, l31 = lane & 31, q5 = lane >> 5;
  int b0 = mb * 32;
  floatx16 acc = fz();
  const u16* brow = h1WT + (size_t)(32 * w + l31) * 32896;
  int br = b0 + l31;
  const u16* seb = se + (size_t)(qoff + br) * 128;
  const u16* hb = hgq + (size_t)br * 32768;
  for (int kk = 0; kk < 257; ++kk){
    int kbase = ks * 4112 + kk * 16;
    const u16* ap = (kbase < 128) ? (seb + kbase + q5 * 8) : (hb + (kbase - 128) + q5 * 8);
    short8 a = *(const short8*)ap;
    short8 bf = *(const short8*)(brow + kbase + q5 * 8);
    acc = MF(a, bf, acc);
  }
#pragma unroll
  for (int reg = 0; reg < 16; ++reg){
    int rr = (reg & 3) + 8 * (reg >> 2) + 4 * q5;
    part[(size_t)ks * nb * 128 + (size_t)(b0 + rr) * 128 + 32 * w + l31] = acc[reg];
  }
}

__global__ __launch_bounds__(256) void k_mlp1red(const float* part, const u16* h1b, float* z1q,
                                                 const int* dflag, int nb){
  int fl = dflag[0];
  int idx = blockIdx.x * 256 + threadIdx.x;    // 0..nb*128-1
  float s = ldf(h1b, idx & 127, fl);
  size_t stride = (size_t)nb * 128;
#pragma unroll
  for (int ks = 0; ks < 8; ++ks) s += part[(size_t)ks * stride + idx];
  z1q[idx] = fmaxf(s, 0.f);
}

__global__ __launch_bounds__(256) void k_mlp2(const float* z1, const u16* h2W, const u16* h2b,
                                              float* z2, const int* dflag){
  int fl = dflag[0];
  int idx = blockIdx.x * 256 + threadIdx.x;    // 0..131071
  int b = idx >> 6, j = idx & 63;
  float s = ldf(h2b, j, fl);
  const float* zr = z1 + (size_t)b * 128;
  for (int k = 0; k < 128; ++k) s += zr[k] * ldf(h2W, (size_t)k * 64 + j, fl);
  z2[idx] = fmaxf(s, 0.f);
}

__global__ __launch_bounds__(256) void k_mlp3(const float* z2, const u16* h3W, const u16* h3b,
                                              void* out, const int* dflag){
  int fl = dflag[0];
  int b = blockIdx.x * 256 + threadIdx.x;      // 0..2047
  float s = ldf(h3b, 0, fl);
  const float* zr = z2 + (size_t)b * 64;
#pragma unroll
  for (int j = 0; j < 64; ++j) s += zr[j] * ldf(h3W, j, fl);
  if (!__builtin_isfinite(s)) s = 0.f;
  if (fl) ((float*)out)[b] = s;
  else    ((u16*)out)[b] = f2b(s);
}

// ---------------- launch ----------------

extern "C" void kernel_launch(void* const* d_in, const int* in_sizes, int n_in,
                              void* d_out, int out_size, void* d_ws, size_t ws_size,
                              hipStream_t stream) {
  const u16* x   = (const u16*)d_in[0];
  const u16* sW  = (const u16*)d_in[1];
  const u16* sb  = (const u16*)d_in[2];
  const u16* hW  = (const u16*)d_in[3];
  const u16* hb  = (const u16*)d_in[4];
  const u16* qW  = (const u16*)d_in[5];
  const u16* qb  = (const u16*)d_in[6];
  const u16* kW  = (const u16*)d_in[7];
  // d_in[8] = kb : cancels in softmax, unused
  const u16* vW  = (const u16*)d_in[9];
  const u16* vb  = (const u16*)d_in[10];
  const u16* lng = (const u16*)d_in[11];
  const u16* lnb = (const u16*)d_in[12];
  const u16* h1W = (const u16*)d_in[13];
  const u16* h1b = (const u16*)d_in[14];
  const u16* h2W = (const u16*)d_in[15];
  const u16* h2b = (const u16*)d_in[16];
  const u16* h3W = (const u16*)d_in[17];
  const u16* h3b = (const u16*)d_in[18];

  // full-pass mode (r5-r8 ran this branch); quarter mode fallback.
  const int nb = (ws_size >= 153600000ull) ? 2048 : 512;
  const int nq = 2048 / nb;

  char* W = (char*)d_ws;
  size_t o = 0;
  u16*   hg    = (u16*)(W + o); o += (size_t)nb * 65536;   // nb*32768*2
  u16*   h1WT  = (u16*)(W + o); o += 8421376;
  u16*   se    = (u16*)(W + o); o += 524288;               // always full 2048x128 bf16
  u16*   MrT   = (u16*)(W + o); o += 65536;
  u16*   vWT   = (u16*)(W + o); o += 65536;
  float* uv    = (float*)(W + o); o += 1024;
  float* part  = (float*)(W + o); o += (size_t)nb * 4096;  // 8 * nb*128 * 4B
  float* z1    = (float*)(W + o); o += 1048576;            // always full
  float* z2    = (float*)(W + o); o += 524288;
  int*   dflag = (int*)(W + o);

  k_detect<<<1, 256, 0, stream>>>(x, dflag);
  k_prepw<<<256, 128, 0, stream>>>(qW, kW, vW, qb, MrT, vWT, uv, dflag);
  k_h1t<<<514, 256, 0, stream>>>(h1W, h1WT, dflag);

  for (int q = 0; q < nq; ++q){
    int qoff = q * nb;
    k_fan<<<nb, 512, 0, stream>>>(x, sW, sb, hW, hb, MrT, uv, vWT, vb,
                                  lng, lnb, hg, se, qoff, dflag);
    k_mlp1<<<dim3(nb / 32, 8), 256, 0, stream>>>(se, hg, h1WT, part, qoff, nb);
    k_mlp1red<<<nb / 2, 256, 0, stream>>>(part, h1b, z1 + (size_t)qoff * 128, dflag, nb);
  }

  k_mlp2<<<512, 256, 0, stream>>>(z1, h2W, h2b, z2, dflag);
  k_mlp3<<<8, 256, 0, stream>>>(z2, h3W, h3b, d_out, dflag);
}

// Round 18
// 924.938 us; speedup vs baseline: 1.9604x; 1.0331x over previous
//
#include <hip/hip_runtime.h>
#include <hip/hip_bf16.h>
#include <cstddef>

// FAN_39273180955145 — round 28. r27 confirmed rule-#20 (unrolling the ep
// loop: 1605->746) but qh-pairing itself is neutral vs r24 (746 vs 739 —
// r24's fully-unrolled et loop already let the compiler interleave chains).
// k_fan reverted to r24 BYTE-EXACT (739us best). New target: the ~207us of
// non-k_fan kernels (22% of wall). k_mlp1 is the heavyweight (~672MB reads:
// 512 blocks x (1.05MB h1WT slice + 0.26MB a-side)). r28 tiles k_mlp1 to
// 64 batches/block (acc0/acc1, STATIC indices, 256 blocks): each brow load
// feeds two MFMA chains -> h1WT traffic halves + 2x MFMA ILP. All other
// kernels unchanged.

typedef unsigned short u16;
typedef unsigned int u32;
typedef short short8 __attribute__((ext_vector_type(8)));
typedef u32 u32x2 __attribute__((ext_vector_type(2)));
typedef float floatx16 __attribute__((ext_vector_type(16)));
typedef float f32x4 __attribute__((ext_vector_type(4)));

__device__ __forceinline__ float b2f(u16 u){ return __uint_as_float(((u32)u) << 16); }
__device__ __forceinline__ u16 f2b(float f){
  __hip_bfloat16 h = __float2bfloat16(f);          // RNE, = old manual round
  return *reinterpret_cast<u16*>(&h);
}
__device__ __forceinline__ u32 pk2(float a, float b){
  float2 t; t.x = a; t.y = b;
  __hip_bfloat162 h = __float22bfloat162_rn(t);    // v_cvt_pk_bf16_f32 (lo=a)
  return *reinterpret_cast<u32*>(&h);
}
// flagged input load: f32 ? fp32 : bf16; non-finite -> 0
__device__ __forceinline__ float ldf(const u16* p, size_t i, int f32){
  float v = f32 ? ((const float*)p)[i] : b2f(p[i]);
  return __builtin_isfinite(v) ? v : 0.f;
}
// [rows][128 bf16] region, 256B rows, 16B-chunk xor swizzle
__device__ __forceinline__ int swz(int row, int ch){ return (row << 8) | ((ch ^ (row & 15)) << 4); }
// [rows][256 bf16] region, 512B rows, 32 chunks; xor low4 only (bijective)
__device__ __forceinline__ int swz2(int row, int ch){ return (row << 9) | ((ch ^ (row & 15)) << 4); }
__device__ __forceinline__ floatx16 fz(){
  floatx16 z;
#pragma unroll
  for (int i = 0; i < 16; ++i) z[i] = 0.f;
  return z;
}
__device__ __forceinline__ floatx16 MF(short8 a, short8 b, floatx16 c){
  return __builtin_amdgcn_mfma_f32_32x32x16_bf16(a, b, c, 0, 0, 0);
}
// C-layout 32x32 tile (by value) -> k-chunk fragment via xor-32 exchange
// (r4-verified). cvt_pk packing + verified __shfl_xor lane exchange.
__device__ __forceinline__ short8 frag_from(floatx16 cv, int half, int q5){
  int r0 = half * 8;
  u32 e01 = pk2(cv[r0 + 0], cv[r0 + 1]);
  u32 e23 = pk2(cv[r0 + 2], cv[r0 + 3]);
  u32 o01 = pk2(cv[r0 + 4], cv[r0 + 5]);
  u32 o23 = pk2(cv[r0 + 6], cv[r0 + 7]);
  u32 s0 = q5 ? e01 : o01;
  u32 s1 = q5 ? e23 : o23;
  u32 r0v = __shfl_xor(s0, 32);
  u32 r1v = __shfl_xor(s1, 32);
  union { u32 u[4]; short8 v; } un;
  un.u[0] = q5 ? r0v : e01;
  un.u[1] = q5 ? r1v : e23;
  un.u[2] = q5 ? o01 : r0v;
  un.u[3] = q5 ? o23 : r1v;
  return un.v;
}

// ---------------- dtype detector (r4-verified) ----------------
__global__ __launch_bounds__(256) void k_detect(const u16* x, int* dflag){
  __shared__ int red[256];
  int t = threadIdx.x, cnt = 0;
  for (int i = t; i < 4096; i += 256){
    u16 v = x[2 * i];
    int e = (v >> 7) & 0xFF;
    if (e == 0xFF || e >= 0x90 || (e > 0 && e <= 0x20)) ++cnt;
  }
  red[t] = cnt;
  __syncthreads();
  for (int off = 128; off > 0; off >>= 1){
    if (t < off) red[t] += red[t + off];
    __syncthreads();
  }
  if (t == 0) dflag[0] = (red[0] > 1000) ? 1 : 0;
}

// ---------------- prep kernels ----------------

// MrowT[a][b] = M'[b,a]; vWT[d][e] = vW[e][d]; uv = u'.
__global__ __launch_bounds__(128) void k_prepw(const u16* qW, const u16* kW, const u16* vW,
                                               const u16* qb, u16* MrT, u16* vWT, float* uv,
                                               const int* dflag){
  int fl = dflag[0];
  int i = blockIdx.x >> 7, f = blockIdx.x & 127, e = threadIdx.x;
  size_t qo = (size_t)(i * 128 + e) * 128;   // qW row e
  size_t ko = (size_t)(i * 128 + f) * 128;   // kW row f
  float m = 0.f;
  for (int d = 0; d < 128; ++d) m += ldf(qW, qo + d, fl) * ldf(kW, ko + d, fl);
  const float RS = 0.08838834764831845f;  // 1/sqrt(128)
  MrT[(i * 128 + f) * 128 + e] = f2b(m * RS);                 // MrowT[f][e] = M'[e,f]
  vWT[(i * 128 + f) * 128 + e] = f2b(ldf(vW, qo + f, fl));    // vWT[d][e] = vW[e][d]
  __shared__ float red[128];
  red[e] = ldf(kW, ko + e, fl) * ldf(qb, (size_t)i * 128 + e, fl);
  __syncthreads();
  for (int off = 64; off > 0; off >>= 1){
    if (e < off) red[e] += red[e + off];
    __syncthreads();
  }
  if (e == 0) uv[i * 128 + f] = red[0] * RS;
}

__global__ __launch_bounds__(256) void k_h1t(const u16* h1W, u16* h1WT, const int* dflag){
  int fl = dflag[0];
  __shared__ u16 tile[64][130];
  int k0 = blockIdx.x * 64, tid = threadIdx.x;
#pragma unroll 4
  for (int it = 0; it < 32; ++it){
    int r = it * 2 + (tid >> 7), c = tid & 127;
    tile[r][c] = f2b(ldf(h1W, (size_t)(k0 + r) * 128 + c, fl));
  }
  __syncthreads();
#pragma unroll 4
  for (int it = 0; it < 32; ++it){
    int idx = it * 256 + tid, n = idx >> 6, kk = idx & 63;
    h1WT[(size_t)n * 32896 + k0 + kk] = tile[kk][n];
  }
}

// -------- fused embed + 2 attention layers; h in LDS; one block = one batch --------
// r24-exact k_fan (739us proven).

__global__ __launch_bounds__(512, 2) void k_fan(
    const u16* x, const u16* sW, const u16* sb, const u16* hW, const u16* hbe,
    const u16* MrT, const float* uv, const u16* vWT, const u16* vb,
    const u16* lng, const u16* lnb,
    u16* hgq, u16* se, int qoff, const int* dflag){
  __shared__ alignas(16) u16 hL[32768];    // h   [256 s][128 f], swz,  64KB
  __shared__ alignas(16) u16 vt[32768];    // vT  [128 d][256 t], swz2, 64KB
  __shared__ alignas(16) float c_all[256]; // c_t + LKOFF - 8, whole layer
  __shared__ float u_lds[128];             // u' for current layer
  int fl = dflag[0];
  int bl = blockIdx.x;
  int b = qoff + bl;
  int tid = threadIdx.x, w = tid >> 6, lane = tid & 63, l31 = lane & 31, q5 = lane >> 5;
  size_t xo = (size_t)b * 272;
  const float LKOFF = -20.72326584f;       // ln(1e-9); off-diag log-kernel value

  // scalar embedding (lanes 0..127)
  if (tid < 128){
    float acc = ldf(sb, tid, fl);
#pragma unroll
    for (int j = 0; j < 16; ++j) acc += ldf(x, xo + j, fl) * ldf(sW, (size_t)j * 128 + tid, fl);
    se[(size_t)b * 128 + tid] = f2b(acc);
  }
  // history embedding -> hL (pair-packed cvt_pk)
#pragma unroll
  for (int it = 0; it < 8; ++it){
    int c = it * 512 + tid, s = c >> 4, ch = c & 15;
    float xv = ldf(x, xo + 16 + s, fl);
    float f[8];
#pragma unroll
    for (int j = 0; j < 8; ++j)
      f[j] = xv * ldf(hW, ch * 8 + j, fl) + ldf(hbe, ch * 8 + j, fl);
    union { u32 u[4]; short8 v; } rr_;
#pragma unroll
    for (int j2 = 0; j2 < 4; ++j2) rr_.u[j2] = pk2(f[2 * j2], f[2 * j2 + 1]);
    *(short8*)((char*)hL + swz(s, ch)) = rr_.v;
  }

  int mtv = w & 3;                         // d-chunk for v producer
  int scol = 32 * w + l31;

#pragma unroll 1
  for (int li = 0; li < 2; ++li){
    const u16* Ta   = MrT + li * 16384;
    const u16* vWTi = vWT + li * 16384;
    if (tid < 128) u_lds[tid] = uv[li * 128 + tid];
    float vbl = ldf(vb, (size_t)li * 128 + 32 * mtv + l31, fl);
    __syncthreads();                 // hL (embed/prev epilogue) + u_lds visible

    // ---- qh_s = h_s.M' into registers: D[e][s] tiles, lane = col = s = scol.
    short8 qhf[8];
#pragma unroll
    for (int et = 0; et < 4; ++et){
      floatx16 qa = fz();
#pragma unroll 2
      for (int kc = 0; kc < 8; ++kc){
        short8 av = *(const short8*)(Ta + (32 * et + l31) * 128 + kc * 16 + q5 * 8);
        short8 bq = *(const short8*)((char*)hL + swz(32 * w + l31, 2 * kc + q5));
        qa = MF(av, bq, qa);
      }
      qhf[2 * et + 0] = frag_from(qa, 0, q5);   // e = 32et + 0..15
      qhf[2 * et + 1] = frag_from(qa, 1, q5);   // e = 32et + 16..31
    }

    // ---- c_all[t] = u'.h_t + (LKOFF - 8)  [softmax baseline folded in]
    {
      int row = 32 * w + l31;
      float dot = 0.f;
#pragma unroll 2
      for (int kc = 0; kc < 8; ++kc){
        int ch = 2 * kc + q5;
        short8 hv = *(const short8*)((char*)hL + swz(row, ch));
#pragma unroll
        for (int j = 0; j < 8; ++j) dot += u_lds[ch * 8 + j] * b2f(hv[j]);
      }
      dot += __shfl_xor(dot, 32);
      if (q5 == 0) c_all[row] = dot + (LKOFF - 8.f);
    }

    // ---- v producer: whole layer, u-PAIRED dual chains sharing avV loads.
    // vt[d][t] = sum_e h[t,e] vW[e,d] + vb[d].
    {
      const u16* Va = vWTi + (32 * mtv + l31) * 128 + q5 * 8;
#pragma unroll 1
      for (int up = 0; up < 2; ++up){
        int tc0 = (w >> 2) * 4 + 2 * up, tc1 = tc0 + 1;
        floatx16 va0 = fz(), va1 = fz();
#pragma unroll 2
        for (int kc = 0; kc < 8; ++kc){
          short8 avV = *(const short8*)(Va + kc * 16);
          short8 bh0 = *(const short8*)((char*)hL + swz(32 * tc0 + l31, 2 * kc + q5));
          short8 bh1 = *(const short8*)((char*)hL + swz(32 * tc1 + l31, 2 * kc + q5));
          va0 = MF(bh0, avV, va0);
          va1 = MF(bh1, avV, va1);
        }
        // D[t][d]: lane = d-col, regs = t; 4 consecutive t -> one 8B chunk
#pragma unroll
        for (int qd = 0; qd < 4; ++qd){
          u32x2 pv;
          pv.x = pk2(va0[4 * qd + 0] + vbl, va0[4 * qd + 1] + vbl);
          pv.y = pk2(va0[4 * qd + 2] + vbl, va0[4 * qd + 3] + vbl);
          *(u32x2*)((char*)vt + swz2(32 * mtv + l31, 4 * tc0 + qd) + 8 * q5) = pv;
        }
#pragma unroll
        for (int qd = 0; qd < 4; ++qd){
          u32x2 pv;
          pv.x = pk2(va1[4 * qd + 0] + vbl, va1[4 * qd + 1] + vbl);
          pv.y = pk2(va1[4 * qd + 2] + vbl, va1[4 * qd + 3] + vbl);
          *(u32x2*)((char*)vt + swz2(32 * mtv + l31, 4 * tc1 + qd) + 8 * q5) = pv;
        }
      }
    }
    __syncthreads();               // vt + c_all complete

    float ls00 = 0.f, ls01 = 0.f, ls10 = 0.f, ls11 = 0.f;
    floatx16 oacc[4];
#pragma unroll
    for (int nt = 0; nt < 4; ++nt) oacc[nt] = fz();

    // ---- consumer: mt-PAIRED scores + exp + P@V; NO internal barriers
#pragma unroll 1
    for (int mtp = 0; mtp < 4; ++mtp){
      int mt0 = 2 * mtp, mt1 = 2 * mtp + 1;
      floatx16 sa0 = fz(), sa1 = fz();
      __builtin_amdgcn_s_setprio(1);
#pragma unroll
      for (int kc = 0; kc < 8; ++kc){
        short8 ah0 = *(const short8*)((char*)hL + swz(32 * mt0 + l31, 2 * kc + q5));
        short8 ah1 = *(const short8*)((char*)hL + swz(32 * mt1 + l31, 2 * kc + q5));
        sa0 = MF(ah0, qhf[kc], sa0);
        sa1 = MF(ah1, qhf[kc], sa1);
      }
      __builtin_amdgcn_s_setprio(0);
      // softmax on sa0 (v = sa + c2[tg]; diag removes folded off-diag LKOFF)
#pragma unroll
      for (int g = 0; g < 4; ++g){
        f32x4 c4 = *(const f32x4*)&c_all[32 * mt0 + 8 * g + 4 * q5];
#pragma unroll
        for (int k = 0; k < 4; ++k){
          int reg = 4 * g + k;
          int tg = 32 * mt0 + 8 * g + 4 * q5 + k;
          float v = sa0[reg] + c4[k];
          if (tg == scol) v -= LKOFF;
          v = fminf(fmaxf(v, -58.f), 42.f);
          float p = __expf(v);
          sa0[reg] = p;
          if (reg & 1) ls01 += p; else ls00 += p;
        }
      }
      // softmax on sa1
#pragma unroll
      for (int g = 0; g < 4; ++g){
        f32x4 c4 = *(const f32x4*)&c_all[32 * mt1 + 8 * g + 4 * q5];
#pragma unroll
        for (int k = 0; k < 4; ++k){
          int reg = 4 * g + k;
          int tg = 32 * mt1 + 8 * g + 4 * q5 + k;
          float v = sa1[reg] + c4[k];
          if (tg == scol) v -= LKOFF;
          v = fminf(fmaxf(v, -58.f), 42.f);
          float p = __expf(v);
          sa1[reg] = p;
          if (reg & 1) ls11 += p; else ls10 += p;
        }
      }
      // pf frags BEFORE the bv loads so sa0/sa1 die here
      short8 pf00 = frag_from(sa0, 0, q5);
      short8 pf01 = frag_from(sa0, 1, q5);
      short8 pf10 = frag_from(sa1, 0, q5);
      short8 pf11 = frag_from(sa1, 1, q5);
      __builtin_amdgcn_s_setprio(1);
#pragma unroll
      for (int nt = 0; nt < 4; ++nt){
        short8 bv;
        bv = *(const short8*)((char*)vt + swz2(32 * nt + l31, 4 * mt0 + 0 + q5));
        oacc[nt] = MF(pf00, bv, oacc[nt]);
        bv = *(const short8*)((char*)vt + swz2(32 * nt + l31, 4 * mt0 + 2 + q5));
        oacc[nt] = MF(pf01, bv, oacc[nt]);
        bv = *(const short8*)((char*)vt + swz2(32 * nt + l31, 4 * mt1 + 0 + q5));
        oacc[nt] = MF(pf10, bv, oacc[nt]);
        bv = *(const short8*)((char*)vt + swz2(32 * nt + l31, 4 * mt1 + 2 + q5));
        oacc[nt] = MF(pf11, bv, oacc[nt]);
      }
      __builtin_amdgcn_s_setprio(0);
    }
    __syncthreads();                   // all hL reads done before epilogue writes

    // ---- epilogue: /l, +residual, LayerNorm, write back to hL (own rows only)
    // group-of-4 batched butterfly (r23): 8 independent shuffles per round.
    float ls_tot = (ls00 + ls01) + (ls10 + ls11);
    float l_run = ls_tot + __shfl_xor(ls_tot, 32);
    float linv = 1.f / l_run;
    float gv[4], bbv[4];
#pragma unroll
    for (int nt = 0; nt < 4; ++nt){
      gv[nt]  = ldf(lng, (size_t)li * 128 + 32 * nt + l31, fl);
      bbv[nt] = ldf(lnb, (size_t)li * 128 + 32 * nt + l31, fl);
    }
#pragma unroll 1
    for (int g4 = 0; g4 < 4; ++g4){
      float s1v[4], s2v[4];
      // pass 1: residual + scale, partials for the 4 regs of this group
#pragma unroll
      for (int j = 0; j < 4; ++j){
        int reg = 4 * g4 + j;
        int rr = (reg & 3) + 8 * (reg >> 2) + 4 * q5;
        int srow = 32 * w + rr;
        float lrv = __shfl(linv, rr);
        float s1 = 0.f, s2 = 0.f;
#pragma unroll
        for (int nt = 0; nt < 4; ++nt){
          int d = 32 * nt + l31;
          float res = b2f(*(const u16*)((char*)hL + swz(srow, d >> 3) + (d & 7) * 2));
          float v = oacc[nt][reg] * lrv + res;
          oacc[nt][reg] = v;
          s1 += v; s2 += v * v;
        }
        s1v[j] = s1; s2v[j] = s2;
      }
      // pass 2: batched butterfly, 8 independent shuffles per round
#pragma unroll
      for (int off = 1; off < 32; off <<= 1){
#pragma unroll
        for (int j = 0; j < 4; ++j){
          s1v[j] += __shfl_xor(s1v[j], off);
          s2v[j] += __shfl_xor(s2v[j], off);
        }
      }
      // pass 3: stats + normalize + write
#pragma unroll
      for (int j = 0; j < 4; ++j){
        int reg = 4 * g4 + j;
        int rr = (reg & 3) + 8 * (reg >> 2) + 4 * q5;
        int srow = 32 * w + rr;
        float mu = s1v[j] * 0.0078125f;
        float rs = rsqrtf(fmaxf(s2v[j] * 0.0078125f - mu * mu, 0.f) + 1e-5f);
#pragma unroll
        for (int nt = 0; nt < 4; ++nt){
          int d = 32 * nt + l31;
          float v = (oacc[nt][reg] - mu) * rs * gv[nt] + bbv[nt];
          *(u16*)((char*)hL + swz(srow, d >> 3) + (d & 7) * 2) = f2b(v);
        }
      }
    }
    __syncthreads();                   // hL update visible before next layer / store
  }

  // final h -> global, coalesced 16B chunks
#pragma unroll
  for (int it = 0; it < 8; ++it){
    int c = it * 512 + tid, row = c >> 4, ch = c & 15;
    *(short8*)(hgq + (size_t)bl * 32768 + row * 128 + ch * 8) =
        *(const short8*)((char*)hL + swz(row, ch));
  }
}

// ---------------- MLP head ----------------
// r28: 64 batches/block (acc0/acc1, static idx) — each brow (h1WT) load
// feeds two MFMA chains: halves h1WT traffic, doubles MFMA ILP.

__global__ __launch_bounds__(256) void k_mlp1(const u16* se, const u16* hgq, const u16* h1WT,
                                              float* part, int qoff, int nb){
  int mb = blockIdx.x, ks = blockIdx.y;
  int tid = threadIdx.x, w = tid >> 6, lane = tid & 63, l31 = lane & 31, q5 = lane >> 5;
  int b0 = mb * 64;
  floatx16 acc0 = fz(), acc1 = fz();
  const u16* brow = h1WT + (size_t)(32 * w + l31) * 32896;
  int br0 = b0 + l31, br1 = b0 + 32 + l31;
  const u16* seb0 = se + (size_t)(qoff + br0) * 128;
  const u16* seb1 = se + (size_t)(qoff + br1) * 128;
  const u16* hb0 = hgq + (size_t)br0 * 32768;
  const u16* hb1 = hgq + (size_t)br1 * 32768;
  for (int kk = 0; kk < 257; ++kk){
    int kbase = ks * 4112 + kk * 16;
    const u16* ap0 = (kbase < 128) ? (seb0 + kbase + q5 * 8) : (hb0 + (kbase - 128) + q5 * 8);
    const u16* ap1 = (kbase < 128) ? (seb1 + kbase + q5 * 8) : (hb1 + (kbase - 128) + q5 * 8);
    short8 bf = *(const short8*)(brow + kbase + q5 * 8);
    short8 a0 = *(const short8*)ap0;
    short8 a1 = *(const short8*)ap1;
    acc0 = MF(a0, bf, acc0);
    acc1 = MF(a1, bf, acc1);
  }
#pragma unroll
  for (int reg = 0; reg < 16; ++reg){
    int rr = (reg & 3) + 8 * (reg >> 2) + 4 * q5;
    part[(size_t)ks * nb * 128 + (size_t)(b0 + rr) * 128 + 32 * w + l31] = acc0[reg];
    part[(size_t)ks * nb * 128 + (size_t)(b0 + 32 + rr) * 128 + 32 * w + l31] = acc1[reg];
  }
}

__global__ __launch_bounds__(256) void k_mlp1red(const float* part, const u16* h1b, float* z1q,
                                                 const int* dflag, int nb){
  int fl = dflag[0];
  int idx = blockIdx.x * 256 + threadIdx.x;    // 0..nb*128-1
  float s = ldf(h1b, idx & 127, fl);
  size_t stride = (size_t)nb * 128;
#pragma unroll
  for (int ks = 0; ks < 8; ++ks) s += part[(size_t)ks * stride + idx];
  z1q[idx] = fmaxf(s, 0.f);
}

__global__ __launch_bounds__(256) void k_mlp2(const float* z1, const u16* h2W, const u16* h2b,
                                              float* z2, const int* dflag){
  int fl = dflag[0];
  int idx = blockIdx.x * 256 + threadIdx.x;    // 0..131071
  int b = idx >> 6, j = idx & 63;
  float s = ldf(h2b, j, fl);
  const float* zr = z1 + (size_t)b * 128;
  for (int k = 0; k < 128; ++k) s += zr[k] * ldf(h2W, (size_t)k * 64 + j, fl);
  z2[idx] = fmaxf(s, 0.f);
}

__global__ __launch_bounds__(256) void k_mlp3(const float* z2, const u16* h3W, const u16* h3b,
                                              void* out, const int* dflag){
  int fl = dflag[0];
  int b = blockIdx.x * 256 + threadIdx.x;      // 0..2047
  float s = ldf(h3b, 0, fl);
  const float* zr = z2 + (size_t)b * 64;
#pragma unroll
  for (int j = 0; j < 64; ++j) s += zr[j] * ldf(h3W, j, fl);
  if (!__builtin_isfinite(s)) s = 0.f;
  if (fl) ((float*)out)[b] = s;
  else    ((u16*)out)[b] = f2b(s);
}

// ---------------- launch ----------------

extern "C" void kernel_launch(void* const* d_in, const int* in_sizes, int n_in,
                              void* d_out, int out_size, void* d_ws, size_t ws_size,
                              hipStream_t stream) {
  const u16* x   = (const u16*)d_in[0];
  const u16* sW  = (const u16*)d_in[1];
  const u16* sb  = (const u16*)d_in[2];
  const u16* hW  = (const u16*)d_in[3];
  const u16* hb  = (const u16*)d_in[4];
  const u16* qW  = (const u16*)d_in[5];
  const u16* qb  = (const u16*)d_in[6];
  const u16* kW  = (const u16*)d_in[7];
  // d_in[8] = kb : cancels in softmax, unused
  const u16* vW  = (const u16*)d_in[9];
  const u16* vb  = (const u16*)d_in[10];
  const u16* lng = (const u16*)d_in[11];
  const u16* lnb = (const u16*)d_in[12];
  const u16* h1W = (const u16*)d_in[13];
  const u16* h1b = (const u16*)d_in[14];
  const u16* h2W = (const u16*)d_in[15];
  const u16* h2b = (const u16*)d_in[16];
  const u16* h3W = (const u16*)d_in[17];
  const u16* h3b = (const u16*)d_in[18];

  // full-pass mode (r5-r8 ran this branch); quarter mode fallback.
  const int nb = (ws_size >= 153600000ull) ? 2048 : 512;
  const int nq = 2048 / nb;

  char* W = (char*)d_ws;
  size_t o = 0;
  u16*   hg    = (u16*)(W + o); o += (size_t)nb * 65536;   // nb*32768*2
  u16*   h1WT  = (u16*)(W + o); o += 8421376;
  u16*   se    = (u16*)(W + o); o += 524288;               // always full 2048x128 bf16
  u16*   MrT   = (u16*)(W + o); o += 65536;
  u16*   vWT   = (u16*)(W + o); o += 65536;
  float* uv    = (float*)(W + o); o += 1024;
  float* part  = (float*)(W + o); o += (size_t)nb * 4096;  // 8 * nb*128 * 4B
  float* z1    = (float*)(W + o); o += 1048576;            // always full
  float* z2    = (float*)(W + o); o += 524288;
  int*   dflag = (int*)(W + o);

  k_detect<<<1, 256, 0, stream>>>(x, dflag);
  k_prepw<<<256, 128, 0, stream>>>(qW, kW, vW, qb, MrT, vWT, uv, dflag);
  k_h1t<<<514, 256, 0, stream>>>(h1W, h1WT, dflag);

  for (int q = 0; q < nq; ++q){
    int qoff = q * nb;
    k_fan<<<nb, 512, 0, stream>>>(x, sW, sb, hW, hb, MrT, uv, vWT, vb,
                                  lng, lnb, hg, se, qoff, dflag);
    k_mlp1<<<dim3(nb / 64, 8), 256, 0, stream>>>(se, hg, h1WT, part, qoff, nb);
    k_mlp1red<<<nb / 2, 256, 0, stream>>>(part, h1b, z1 + (size_t)qoff * 128, dflag, nb);
  }

  k_mlp2<<<512, 256, 0, stream>>>(z1, h2W, h2b, z2, dflag);
  k_mlp3<<<8, 256, 0, stream>>>(z2, h3W, h3b, d_out, dflag);
}